// Round 10
// baseline (149.788 us; speedup 1.0000x reference)
//
#include <hip/hip_runtime.h>
#include <hip/hip_bf16.h>

#define NN 50000
#define NE 800000
#define D 128
#define NEG_SLOPE 0.01f
#define LN_EPS 1e-5f

#define NPB 256                 // nodes per bucket (bucket = dst >> 8)
#define NB 196                  // ceil(NN / NPB); NB*256 = 50176
#define CAP 6144                // per-bucket bedge capacity (avg 4082, max ~4340)
#define ECH 8192                // edges per bucket-workgroup (no LDS stage now)
#define NCH ((NE + ECH - 1) / ECH)  // 98
#define NDEG 256                // deg-atomic workgroups in fused1
#define NGEMM ((NN + 63) / 64)  // 782

typedef __attribute__((ext_vector_type(8))) short bf16x8;
typedef __attribute__((ext_vector_type(4))) float f32x4;
typedef __attribute__((ext_vector_type(4))) int i32x4;

// f32 -> bf16 round-to-nearest-even (finite values)
__device__ inline unsigned short f2bf(float f) {
    unsigned u = __float_as_uint(f);
    unsigned r = 0x7FFFu + ((u >> 16) & 1u);
    return (unsigned short)((u + r) >> 16);
}
// unpack one dword = 2 bf16 -> 2 floats
__device__ inline void bf2x(unsigned u, float& lo, float& hi) {
    lo = __uint_as_float(u << 16);
    hi = __uint_as_float(u & 0xFFFF0000u);
}

// ---------------- phase 1: bucket_scatter || deg atomics || GEMM1, one kernel ----------------

struct BucketLDS {
    int hist[NB], lcur[NB], gbase[NB];
    int tmp[256];
};
struct GemmLDS {
    unsigned short a[64 * 128];            // 16 KB (A tile only; W read from global/L1)
};
union FusedLDS { BucketLDS b; GemmLDS g; };

// GEMM1 body: A staged (f32->bf16, swizzled) in 16 KB LDS; B fragments loaded
// directly from packed WT[n][k] in global (32 KB, L1-resident after warmup).
__device__ inline void gemm_body(GemmLDS& L, const float* __restrict__ A,
                                 const unsigned short* __restrict__ WT,
                                 unsigned short* __restrict__ out, int m0, int n, int t) {
    #pragma unroll
    for (int it = 0; it < 4; ++it) {
        int idx = it * 256 + t;
        int row = idx >> 4, c = idx & 15;
        int grow = m0 + row;
        uint4 w = make_uint4(0u, 0u, 0u, 0u);
        if (grow < n) {
            float4 v0 = *(const float4*)&A[(size_t)grow * D + c * 8];
            float4 v1 = *(const float4*)&A[(size_t)grow * D + c * 8 + 4];
            w.x = (unsigned)f2bf(v0.x) | ((unsigned)f2bf(v0.y) << 16);
            w.y = (unsigned)f2bf(v0.z) | ((unsigned)f2bf(v0.w) << 16);
            w.z = (unsigned)f2bf(v1.x) | ((unsigned)f2bf(v1.y) << 16);
            w.w = (unsigned)f2bf(v1.z) | ((unsigned)f2bf(v1.w) << 16);
        }
        int byte = (row * 256 + c * 16) ^ ((row & 7) << 4);
        *(uint4*)((char*)L.a + byte) = w;
    }
    __syncthreads();

    int wv = t >> 6, l = t & 63;
    int lrow = l & 15, lgrp = l >> 4;
    int arow = wv * 16 + lrow;

    f32x4 acc[8];
    #pragma unroll
    for (int nf = 0; nf < 8; ++nf) acc[nf] = (f32x4){0.f, 0.f, 0.f, 0.f};

    #pragma unroll
    for (int kk = 0; kk < 4; ++kk) {
        int abyte = (arow * 256 + kk * 64 + lgrp * 16) ^ ((arow & 7) << 4);
        bf16x8 afrag = *(bf16x8*)((char*)L.a + abyte);
        #pragma unroll
        for (int nf = 0; nf < 8; ++nf) {
            int bcol = nf * 16 + lrow;
            bf16x8 bfrag = *(const bf16x8*)&WT[bcol * 128 + kk * 32 + lgrp * 8];
            acc[nf] = __builtin_amdgcn_mfma_f32_16x16x32_bf16(afrag, bfrag, acc[nf], 0, 0, 0);
        }
    }

    #pragma unroll
    for (int nf = 0; nf < 8; ++nf) {
        #pragma unroll
        for (int r = 0; r < 4; ++r) {
            int grow = m0 + wv * 16 + lgrp * 4 + r;
            if (grow < n) out[(size_t)grow * D + nf * 16 + lrow] = f2bf(acc[nf][r]);
        }
    }
}

__global__ __launch_bounds__(256) void fused1(const int* __restrict__ src,
                                              const int* __restrict__ dst,
                                              int* __restrict__ bcursor,
                                              int2* __restrict__ bedge,
                                              int* __restrict__ deg,
                                              const float* __restrict__ x,
                                              const unsigned short* __restrict__ wt1,
                                              unsigned short* __restrict__ hbf) {
    __shared__ FusedLDS u;
    int bid = blockIdx.x, t = threadIdx.x;

    if (bid < NCH) {
        // ---- bucket scatter: hist -> reserve -> direct global scatter ----
        BucketLDS& L = u.b;
        int e0 = bid * ECH;
        int ecnt = min(ECH, NE - e0);
        if (t < NB) L.hist[t] = 0;
        __syncthreads();
        for (int k = t; k < ecnt; k += 256) atomicAdd(&L.hist[dst[e0 + k] >> 8], 1);
        __syncthreads();
        if (t < NB) {
            L.gbase[t] = atomicAdd(&bcursor[t], L.hist[t]);  // reserve exclusive run
            L.lcur[t] = 0;
        }
        __syncthreads();
        for (int k = t; k < ecnt; k += 256) {
            int s = src[e0 + k], d = dst[e0 + k];
            int b = d >> 8;
            int p = atomicAdd(&L.lcur[b], 1);
            bedge[(size_t)b * CAP + L.gbase[b] + p] = make_int2(s, d);
        }
    } else if (bid < NCH + NDEG) {
        // ---- degree count (global atomics; overlapped, latency hidden) ----
        for (int k = (bid - NCH) * 256 + t; k < NE; k += NDEG * 256)
            atomicAdd(&deg[dst[k]], 1);
    } else {
        // ---- GEMM1: hbf = bf16(x @ W1) ----
        gemm_body(u.g, x, wt1, hbf, (bid - NCH - NDEG) * 64, NN, t);
    }
}

// ---------------- phase 2: dinv + rowinfo + padded CSR scatter, one kernel ----------------
__global__ __launch_bounds__(256) void fused2(const int2* __restrict__ bedge,
                                              const int* __restrict__ bcnt,
                                              const int* __restrict__ deg,
                                              float* __restrict__ dinv,
                                              int2* __restrict__ rowinfo,
                                              int* __restrict__ ticket,
                                              int2* __restrict__ csr_pair) {
    __shared__ int tmp[256];
    __shared__ int rl[NPB], cur[NPB];
    __shared__ float sdinv[NPB];
    __shared__ int base;
    int b = blockIdx.x, t = threadIdx.x;
    int node = b * NPB + t;
    int dg = (node < NN) ? deg[node] : 0;
    float dv = rsqrtf((float)(dg + 1));          // +1: self-loop
    sdinv[t] = dv;
    int pdeg = (dg + 7) & ~7;                    // pad to multiple of 8
    tmp[t] = pdeg;
    __syncthreads();
    for (int off = 1; off < 256; off <<= 1) {
        int uu = (t >= off) ? tmp[t - off] : 0;
        __syncthreads();
        tmp[t] += uu;
        __syncthreads();
    }
    if (t == 255) base = atomicAdd(ticket, tmp[255]);
    __syncthreads();
    int start = base + tmp[t] - pdeg;
    rl[t] = start;
    cur[t] = 0;
    if (node < NN) {
        dinv[node] = dv;
        rowinfo[node] = make_int2(start, pdeg);
    }
    __syncthreads();
    int s0 = b * CAP, s1 = s0 + bcnt[b];
    for (int k = s0 + t; k < s1; k += 256) {
        int2 eg = bedge[k];
        int li = eg.y & 255;
        int p = atomicAdd(&cur[li], 1);
        int ds = deg[eg.x];                      // L2-hot 200 KB table
        float coef = rsqrtf((float)(ds + 1)) * sdinv[li];
        csr_pair[rl[li] + p] = make_int2(eg.x, __float_as_int(coef));
    }
    __syncthreads();
    int dgc = cur[t];
    int pend = (dgc + 7) & ~7;
    int selfsrc = (node < NN) ? node : 0;
    for (int k = dgc; k < pend; ++k)
        csr_pair[rl[t] + k] = make_int2(selfsrc, 0);
}

// Pack W1 and W2 (f32 [k][n]) -> bf16 [n][k] in ONE launch.
__global__ void wt_pack2(const float* __restrict__ W1, const float* __restrict__ W2,
                         unsigned short* __restrict__ WT1, unsigned short* __restrict__ WT2) {
    int tid = blockIdx.x * 256 + threadIdx.x;
    const float* W = (tid < D * D) ? W1 : W2;
    unsigned short* WT = (tid < D * D) ? WT1 : WT2;
    int id = tid & (D * D - 1);
    int nn = id & 127, k = id >> 7;
    WT[nn * 128 + k] = f2bf(W[k * 128 + nn]);
}

// ---------------- aggregation helpers ----------------

// one 8-edge block: 4 nt pair-loads + 8 gathers + 16 fma
__device__ inline void agg8(const unsigned* __restrict__ h, const int2* __restrict__ csr_pair,
                            int e, int lane, float& accx, float& accy) {
    i32x4 q0 = __builtin_nontemporal_load((const i32x4*)(csr_pair + e + 0));
    i32x4 q1 = __builtin_nontemporal_load((const i32x4*)(csr_pair + e + 2));
    i32x4 q2 = __builtin_nontemporal_load((const i32x4*)(csr_pair + e + 4));
    i32x4 q3 = __builtin_nontemporal_load((const i32x4*)(csr_pair + e + 6));
    unsigned g0 = h[(size_t)q0[0] * (D / 2) + lane];
    unsigned g1 = h[(size_t)q0[2] * (D / 2) + lane];
    unsigned g2 = h[(size_t)q1[0] * (D / 2) + lane];
    unsigned g3 = h[(size_t)q1[2] * (D / 2) + lane];
    unsigned g4 = h[(size_t)q2[0] * (D / 2) + lane];
    unsigned g5 = h[(size_t)q2[2] * (D / 2) + lane];
    unsigned g6 = h[(size_t)q3[0] * (D / 2) + lane];
    unsigned g7 = h[(size_t)q3[2] * (D / 2) + lane];
    float ax, ay, c;
    c = __int_as_float(q0[1]); bf2x(g0, ax, ay); accx = fmaf(c, ax, accx); accy = fmaf(c, ay, accy);
    c = __int_as_float(q0[3]); bf2x(g1, ax, ay); accx = fmaf(c, ax, accx); accy = fmaf(c, ay, accy);
    c = __int_as_float(q1[1]); bf2x(g2, ax, ay); accx = fmaf(c, ax, accx); accy = fmaf(c, ay, accy);
    c = __int_as_float(q1[3]); bf2x(g3, ax, ay); accx = fmaf(c, ax, accx); accy = fmaf(c, ay, accy);
    c = __int_as_float(q2[1]); bf2x(g4, ax, ay); accx = fmaf(c, ax, accx); accy = fmaf(c, ay, accy);
    c = __int_as_float(q2[3]); bf2x(g5, ax, ay); accx = fmaf(c, ax, accx); accy = fmaf(c, ay, accy);
    c = __int_as_float(q3[1]); bf2x(g6, ax, ay); accx = fmaf(c, ax, accx); accy = fmaf(c, ay, accy);
    c = __int_as_float(q3[3]); bf2x(g7, ax, ay); accx = fmaf(c, ax, accx); accy = fmaf(c, ay, accy);
}

// joint 2-node 8+8 edge loop (16 gathers in flight), then drains
__device__ inline void agg_2node(const unsigned* __restrict__ h,
                                 const int2* __restrict__ csr_pair,
                                 int eA, int eA1, int eB, int eB1, int lane,
                                 float& aAx, float& aAy, float& aBx, float& aBy) {
    while (eA < eA1 && eB < eB1) {
        i32x4 qA0 = __builtin_nontemporal_load((const i32x4*)(csr_pair + eA + 0));
        i32x4 qA1 = __builtin_nontemporal_load((const i32x4*)(csr_pair + eA + 2));
        i32x4 qA2 = __builtin_nontemporal_load((const i32x4*)(csr_pair + eA + 4));
        i32x4 qA3 = __builtin_nontemporal_load((const i32x4*)(csr_pair + eA + 6));
        i32x4 qB0 = __builtin_nontemporal_load((const i32x4*)(csr_pair + eB + 0));
        i32x4 qB1 = __builtin_nontemporal_load((const i32x4*)(csr_pair + eB + 2));
        i32x4 qB2 = __builtin_nontemporal_load((const i32x4*)(csr_pair + eB + 4));
        i32x4 qB3 = __builtin_nontemporal_load((const i32x4*)(csr_pair + eB + 6));
        unsigned gA0 = h[(size_t)qA0[0] * (D / 2) + lane];
        unsigned gA1 = h[(size_t)qA0[2] * (D / 2) + lane];
        unsigned gA2 = h[(size_t)qA1[0] * (D / 2) + lane];
        unsigned gA3 = h[(size_t)qA1[2] * (D / 2) + lane];
        unsigned gA4 = h[(size_t)qA2[0] * (D / 2) + lane];
        unsigned gA5 = h[(size_t)qA2[2] * (D / 2) + lane];
        unsigned gA6 = h[(size_t)qA3[0] * (D / 2) + lane];
        unsigned gA7 = h[(size_t)qA3[2] * (D / 2) + lane];
        unsigned gB0 = h[(size_t)qB0[0] * (D / 2) + lane];
        unsigned gB1 = h[(size_t)qB0[2] * (D / 2) + lane];
        unsigned gB2 = h[(size_t)qB1[0] * (D / 2) + lane];
        unsigned gB3 = h[(size_t)qB1[2] * (D / 2) + lane];
        unsigned gB4 = h[(size_t)qB2[0] * (D / 2) + lane];
        unsigned gB5 = h[(size_t)qB2[2] * (D / 2) + lane];
        unsigned gB6 = h[(size_t)qB3[0] * (D / 2) + lane];
        unsigned gB7 = h[(size_t)qB3[2] * (D / 2) + lane];
        float ax, ay, c;
        c = __int_as_float(qA0[1]); bf2x(gA0, ax, ay); aAx = fmaf(c, ax, aAx); aAy = fmaf(c, ay, aAy);
        c = __int_as_float(qA0[3]); bf2x(gA1, ax, ay); aAx = fmaf(c, ax, aAx); aAy = fmaf(c, ay, aAy);
        c = __int_as_float(qA1[1]); bf2x(gA2, ax, ay); aAx = fmaf(c, ax, aAx); aAy = fmaf(c, ay, aAy);
        c = __int_as_float(qA1[3]); bf2x(gA3, ax, ay); aAx = fmaf(c, ax, aAx); aAy = fmaf(c, ay, aAy);
        c = __int_as_float(qA2[1]); bf2x(gA4, ax, ay); aAx = fmaf(c, ax, aAx); aAy = fmaf(c, ay, aAy);
        c = __int_as_float(qA2[3]); bf2x(gA5, ax, ay); aAx = fmaf(c, ax, aAx); aAy = fmaf(c, ay, aAy);
        c = __int_as_float(qA3[1]); bf2x(gA6, ax, ay); aAx = fmaf(c, ax, aAx); aAy = fmaf(c, ay, aAy);
        c = __int_as_float(qA3[3]); bf2x(gA7, ax, ay); aAx = fmaf(c, ax, aAx); aAy = fmaf(c, ay, aAy);
        c = __int_as_float(qB0[1]); bf2x(gB0, ax, ay); aBx = fmaf(c, ax, aBx); aBy = fmaf(c, ay, aBy);
        c = __int_as_float(qB0[3]); bf2x(gB1, ax, ay); aBx = fmaf(c, ax, aBx); aBy = fmaf(c, ay, aBy);
        c = __int_as_float(qB1[1]); bf2x(gB2, ax, ay); aBx = fmaf(c, ax, aBx); aBy = fmaf(c, ay, aBy);
        c = __int_as_float(qB1[3]); bf2x(gB3, ax, ay); aBx = fmaf(c, ax, aBx); aBy = fmaf(c, ay, aBy);
        c = __int_as_float(qB2[1]); bf2x(gB4, ax, ay); aBx = fmaf(c, ax, aBx); aBy = fmaf(c, ay, aBy);
        c = __int_as_float(qB2[3]); bf2x(gB5, ax, ay); aBx = fmaf(c, ax, aBx); aBy = fmaf(c, ay, aBy);
        c = __int_as_float(qB3[1]); bf2x(gB6, ax, ay); aBx = fmaf(c, ax, aBx); aBy = fmaf(c, ay, aBy);
        c = __int_as_float(qB3[3]); bf2x(gB7, ax, ay); aBx = fmaf(c, ax, aBx); aBy = fmaf(c, ay, aBy);
        eA += 8; eB += 8;
    }
    while (eA < eA1) { agg8(h, csr_pair, eA, lane, aAx, aAy); eA += 8; }
    while (eB < eB1) { agg8(h, csr_pair, eB, lane, aBx, aBy); eB += 8; }
}

// ---------------- layer 1: agg + bias + leaky + residual + LN1 + GEMM2 (fused MFMA) ----------------
__global__ __launch_bounds__(512) void agg_ln1_gemm(const unsigned* __restrict__ h,
                                                    const float* __restrict__ x,
                                                    const float* __restrict__ bias,
                                                    const float* __restrict__ gamma,
                                                    const float* __restrict__ beta,
                                                    const float* __restrict__ dinv,
                                                    const int2* __restrict__ rowinfo,
                                                    const int2* __restrict__ csr_pair,
                                                    const unsigned short* __restrict__ wt2,
                                                    unsigned short* __restrict__ hbf2) {
    __shared__ __align__(16) unsigned short w_lds[128 * 128];  // 32 KB
    __shared__ __align__(16) unsigned short a_lds[16 * 128];   // 4 KB
    int t = threadIdx.x;

    #pragma unroll
    for (int it = 0; it < 4; ++it) {
        int idx = it * 512 + t;
        int row = idx >> 4, c = idx & 15;
        uint4 v = *(const uint4*)&wt2[row * 128 + c * 8];
        int byte = (row * 256 + c * 16) ^ ((row & 7) << 4);
        *(uint4*)((char*)w_lds + byte) = v;
    }

    int wid = t >> 6, lane = t & 63;
    int iA = blockIdx.x * 16 + wid * 2;   // NN = 50000 = 3125 * 16, exact
    int iB = iA + 1;
    float diA = dinv[iA], diB = dinv[iB];

    float hx, hy;
    bf2x(h[(size_t)iA * (D / 2) + lane], hx, hy);
    float aAx = diA * diA * hx, aAy = diA * diA * hy;
    bf2x(h[(size_t)iB * (D / 2) + lane], hx, hy);
    float aBx = diB * diB * hx, aBy = diB * diB * hy;

    int2 riA = rowinfo[iA];
    int2 riB = rowinfo[iB];
    int eA = __builtin_amdgcn_readfirstlane(riA.x);
    int eA1 = eA + __builtin_amdgcn_readfirstlane(riA.y);
    int eB = __builtin_amdgcn_readfirstlane(riB.x);
    int eB1 = eB + __builtin_amdgcn_readfirstlane(riB.y);
    agg_2node(h, csr_pair, eA, eA1, eB, eB1, lane, aAx, aAy, aBx, aBy);

    float2 bv = *(const float2*)&bias[2 * lane];
    float2 gv = *(const float2*)&gamma[2 * lane];
    float2 bt = *(const float2*)&beta[2 * lane];

    aAx += bv.x; aAy += bv.y;
    aBx += bv.x; aBy += bv.y;
    aAx = aAx > 0.f ? aAx : NEG_SLOPE * aAx;
    aAy = aAy > 0.f ? aAy : NEG_SLOPE * aAy;
    aBx = aBx > 0.f ? aBx : NEG_SLOPE * aBx;
    aBy = aBy > 0.f ? aBy : NEG_SLOPE * aBy;

    size_t rowA = (size_t)iA * D + 2 * lane;
    size_t rowB = (size_t)iB * D + 2 * lane;
    float2 xA = *(const float2*)&x[rowA];
    float2 xB = *(const float2*)&x[rowB];
    float vA0 = aAx + xA.x, vA1 = aAy + xA.y;
    float vB0 = aBx + xB.x, vB1 = aBy + xB.y;

    float sA1 = vA0 + vA1, sA2 = vA0 * vA0 + vA1 * vA1;
    float sB1 = vB0 + vB1, sB2 = vB0 * vB0 + vB1 * vB1;
    #pragma unroll
    for (int off = 1; off < 64; off <<= 1) {
        sA1 += __shfl_xor(sA1, off, 64);
        sA2 += __shfl_xor(sA2, off, 64);
        sB1 += __shfl_xor(sB1, off, 64);
        sB2 += __shfl_xor(sB2, off, 64);
    }
    float muA = sA1 * (1.f / 128.f);
    float varA = fmaxf(sA2 * (1.f / 128.f) - muA * muA, 0.f);
    float rsA = rsqrtf(varA + LN_EPS);
    float muB = sB1 * (1.f / 128.f);
    float varB = fmaxf(sB2 * (1.f / 128.f) - muB * muB, 0.f);
    float rsB = rsqrtf(varB + LN_EPS);

    float oA0 = (vA0 - muA) * rsA * gv.x + bt.x;
    float oA1 = (vA1 - muA) * rsA * gv.y + bt.y;
    float oB0 = (vB0 - muB) * rsB * gv.x + bt.x;
    float oB1 = (vB1 - muB) * rsB * gv.y + bt.y;

    int rA = wid * 2, rB = wid * 2 + 1;
    unsigned dwA = (unsigned)f2bf(oA0) | ((unsigned)f2bf(oA1) << 16);
    unsigned dwB = (unsigned)f2bf(oB0) | ((unsigned)f2bf(oB1) << 16);
    int byteA = (rA * 256 + lane * 4) ^ ((rA & 7) << 4);
    int byteB = (rB * 256 + lane * 4) ^ ((rB & 7) << 4);
    *(unsigned*)((char*)a_lds + byteA) = dwA;
    *(unsigned*)((char*)a_lds + byteB) = dwB;
    __syncthreads();

    int lrow = lane & 15, lgrp = lane >> 4;
    f32x4 acc = (f32x4){0.f, 0.f, 0.f, 0.f};
    #pragma unroll
    for (int kk = 0; kk < 4; ++kk) {
        int abyte = (lrow * 256 + kk * 64 + lgrp * 16) ^ ((lrow & 7) << 4);
        bf16x8 afrag = *(bf16x8*)((char*)a_lds + abyte);
        int bcol = wid * 16 + lrow;
        int bbyte = (bcol * 256 + kk * 64 + lgrp * 16) ^ ((bcol & 7) << 4);
        bf16x8 bfrag = *(bf16x8*)((char*)w_lds + bbyte);
        acc = __builtin_amdgcn_mfma_f32_16x16x32_bf16(afrag, bfrag, acc, 0, 0, 0);
    }
    #pragma unroll
    for (int r = 0; r < 4; ++r) {
        int grow = blockIdx.x * 16 + lgrp * 4 + r;
        hbf2[(size_t)grow * D + wid * 16 + lrow] = f2bf(acc[r]);
    }
}

// ---------------- layer 2: agg + bias + residual + LN2 + leaky (final f32 out) ----------------
__global__ __launch_bounds__(256) void agg_ln2(const unsigned* __restrict__ h,
                                               const float* __restrict__ x,
                                               const float* __restrict__ bias,
                                               const float* __restrict__ gamma,
                                               const float* __restrict__ beta,
                                               const float* __restrict__ dinv,
                                               const int2* __restrict__ rowinfo,
                                               const int2* __restrict__ csr_pair,
                                               float* __restrict__ out) {
    int wid = threadIdx.x >> 6;
    int lane = threadIdx.x & 63;
    int iA = blockIdx.x * 8 + wid * 2;   // NN = 50000 = 6250 * 8, exact
    int iB = iA + 1;
    float diA = dinv[iA], diB = dinv[iB];

    float hx, hy;
    bf2x(h[(size_t)iA * (D / 2) + lane], hx, hy);
    float aAx = diA * diA * hx, aAy = diA * diA * hy;
    bf2x(h[(size_t)iB * (D / 2) + lane], hx, hy);
    float aBx = diB * diB * hx, aBy = diB * diB * hy;

    int2 riA = rowinfo[iA];
    int2 riB = rowinfo[iB];
    int eA = __builtin_amdgcn_readfirstlane(riA.x);
    int eA1 = eA + __builtin_amdgcn_readfirstlane(riA.y);
    int eB = __builtin_amdgcn_readfirstlane(riB.x);
    int eB1 = eB + __builtin_amdgcn_readfirstlane(riB.y);
    agg_2node(h, csr_pair, eA, eA1, eB, eB1, lane, aAx, aAy, aBx, aBy);

    float2 bv = *(const float2*)&bias[2 * lane];
    float2 gv = *(const float2*)&gamma[2 * lane];
    float2 bt = *(const float2*)&beta[2 * lane];

    aAx += bv.x; aAy += bv.y;
    aBx += bv.x; aBy += bv.y;
    size_t rowA = (size_t)iA * D + 2 * lane;
    size_t rowB = (size_t)iB * D + 2 * lane;
    float2 xA = *(const float2*)&x[rowA];
    float2 xB = *(const float2*)&x[rowB];
    float vA0 = aAx + xA.x, vA1 = aAy + xA.y;
    float vB0 = aBx + xB.x, vB1 = aBy + xB.y;

    float sA1 = vA0 + vA1, sA2 = vA0 * vA0 + vA1 * vA1;
    float sB1 = vB0 + vB1, sB2 = vB0 * vB0 + vB1 * vB1;
    #pragma unroll
    for (int off = 1; off < 64; off <<= 1) {
        sA1 += __shfl_xor(sA1, off, 64);
        sA2 += __shfl_xor(sA2, off, 64);
        sB1 += __shfl_xor(sB1, off, 64);
        sB2 += __shfl_xor(sB2, off, 64);
    }
    float muA = sA1 * (1.f / 128.f);
    float varA = fmaxf(sA2 * (1.f / 128.f) - muA * muA, 0.f);
    float rsA = rsqrtf(varA + LN_EPS);
    float muB = sB1 * (1.f / 128.f);
    float varB = fmaxf(sB2 * (1.f / 128.f) - muB * muB, 0.f);
    float rsB = rsqrtf(varB + LN_EPS);

    float oA0 = (vA0 - muA) * rsA * gv.x + bt.x;
    float oA1 = (vA1 - muA) * rsA * gv.y + bt.y;
    float oB0 = (vB0 - muB) * rsB * gv.x + bt.x;
    float oB1 = (vB1 - muB) * rsB * gv.y + bt.y;
    oA0 = oA0 > 0.f ? oA0 : NEG_SLOPE * oA0;
    oA1 = oA1 > 0.f ? oA1 : NEG_SLOPE * oA1;
    oB0 = oB0 > 0.f ? oB0 : NEG_SLOPE * oB0;
    oB1 = oB1 > 0.f ? oB1 : NEG_SLOPE * oB1;
    *(float2*)&out[rowA] = make_float2(oA0, oA1);
    *(float2*)&out[rowB] = make_float2(oB0, oB1);
}

extern "C" void kernel_launch(void* const* d_in, const int* in_sizes, int n_in,
                              void* d_out, int out_size, void* d_ws, size_t ws_size,
                              hipStream_t stream) {
    const float* x    = (const float*)d_in[0];
    const int*   ei   = (const int*)d_in[1];   // [2, NE]: row0 src, row1 dst
    const float* W1   = (const float*)d_in[2];
    const float* b1   = (const float*)d_in[3];
    const float* ln1g = (const float*)d_in[4];
    const float* ln1b = (const float*)d_in[5];
    const float* W2   = (const float*)d_in[6];
    const float* b2   = (const float*)d_in[7];
    const float* ln2g = (const float*)d_in[8];
    const float* ln2b = (const float*)d_in[9];
    float* out = (float*)d_out;

    const int* srcp = ei;
    const int* dstp = ei + NE;

    char* ws = (char*)d_ws;
    size_t p = 0;
    auto alloc = [&](size_t bytes) {
        char* r = ws + p;
        p += (bytes + 255) & ~(size_t)255;
        return r;
    };
    // deg + bcursor/ticket adjacent -> single memset
    int*   deg      = (int*)alloc(NN * 4);
    int*   bcursor  = (int*)alloc((NB + 1) * 4);         // [NB] = ticket
    int2*  rowinfo  = (int2*)alloc((size_t)NN * 8);
    float* dinv     = (float*)alloc(NN * 4);
    int2*  bedge    = (int2*)alloc((size_t)NB * CAP * 8);
    int2*  csr_pair = (int2*)alloc(((size_t)NE + 8 * NN) * 8);  // padded CSR
    unsigned short* hbf  = (unsigned short*)alloc((size_t)NN * D * 2);
    unsigned short* hbf2 = (unsigned short*)alloc((size_t)NN * D * 2);
    unsigned short* wt1  = (unsigned short*)alloc(D * D * 2);
    unsigned short* wt2  = (unsigned short*)alloc(D * D * 2);

    size_t zbytes = (char*)rowinfo - (char*)deg;         // deg + bcursor region
    hipMemsetAsync(deg, 0, zbytes, stream);

    wt_pack2<<<2 * D * D / 256, 256, 0, stream>>>(W1, W2, wt1, wt2);

    // Phase 1: bucket scatter || degree atomics || GEMM1
    fused1<<<NCH + NDEG + NGEMM, 256, 0, stream>>>(srcp, dstp, bcursor, bedge, deg,
                                                   x, wt1, hbf);

    // Phase 2: dinv + rowinfo + padded CSR
    fused2<<<NB, 256, 0, stream>>>(bedge, bcursor, deg, dinv, rowinfo,
                                   &bcursor[NB], csr_pair);

    // Layer 1 (+ fused GEMM2): hbf2 = bf16( LN1(leaky(agg(hbf)+b1)+x) @ W2 )
    agg_ln1_gemm<<<NN / 16, 512, 0, stream>>>((const unsigned*)hbf, x, b1, ln1g, ln1b,
                                              dinv, rowinfo, csr_pair, wt2, hbf2);

    // Layer 2: out = leaky(LN2(agg(hbf2)+b2+x))
    agg_ln2<<<NN / 8, 256, 0, stream>>>((const unsigned*)hbf2, x, b2, ln2g, ln2b,
                                        dinv, rowinfo, csr_pair, out);
}

// Round 11
// 133.703 us; speedup vs baseline: 1.1203x; 1.1203x over previous
//
#include <hip/hip_runtime.h>
#include <hip/hip_bf16.h>

#define NN 50000
#define NE 800000
#define D 128
#define NEG_SLOPE 0.01f
#define LN_EPS 1e-5f

#define NPB 256                 // nodes per bucket (bucket = dst >> 8)
#define NB 196                  // ceil(NN / NPB); NB*256 = 50176
#define CAP 6144                // per-bucket bedge capacity (avg 4082, max ~4340)
#define ECH 8192                // edges per bucket-workgroup
#define NCH ((NE + ECH - 1) / ECH)  // 98

typedef __attribute__((ext_vector_type(8))) short bf16x8;
typedef __attribute__((ext_vector_type(4))) float f32x4;
typedef __attribute__((ext_vector_type(4))) int i32x4;

// f32 -> bf16 round-to-nearest-even (finite values)
__device__ inline unsigned short f2bf(float f) {
    unsigned u = __float_as_uint(f);
    unsigned r = 0x7FFFu + ((u >> 16) & 1u);
    return (unsigned short)((u + r) >> 16);
}
// unpack one dword = 2 bf16 -> 2 floats
__device__ inline void bf2x(unsigned u, float& lo, float& hi) {
    lo = __uint_as_float(u << 16);
    hi = __uint_as_float(u & 0xFFFF0000u);
}

// ---------------- CSR build: lean kernels, full occupancy each ----------------

// Direct bucket scatter: LDS hist -> reserve global run -> direct global writes.
// Per-(block,bucket) runs are contiguous; L2 assembles full lines. LDS ~2.4 KB.
__global__ __launch_bounds__(256) void bucket_scatter(const int* __restrict__ src,
                                                      const int* __restrict__ dst,
                                                      int* __restrict__ bcursor,
                                                      int2* __restrict__ bedge) {
    __shared__ int hist[NB], lcur[NB], gbase[NB];
    int t = threadIdx.x;
    int e0 = blockIdx.x * ECH;
    int ecnt = min(ECH, NE - e0);
    if (t < NB) hist[t] = 0;
    __syncthreads();
    for (int k = t; k < ecnt; k += 256) atomicAdd(&hist[dst[e0 + k] >> 8], 1);
    __syncthreads();
    if (t < NB) {
        gbase[t] = atomicAdd(&bcursor[t], hist[t]);   // reserve exclusive run
        lcur[t] = 0;
    }
    __syncthreads();
    for (int k = t; k < ecnt; k += 256) {
        int s = src[e0 + k], d = dst[e0 + k];
        int b = d >> 8;
        int p = atomicAdd(&lcur[b], 1);
        bedge[(size_t)b * CAP + gbase[b] + p] = make_int2(s, d);
    }
}

// Per-bucket node histogram from bedge -> dinv + rowinfo (padded run via ticket).
__global__ __launch_bounds__(256) void node_count(const int2* __restrict__ bedge,
                                                  const int* __restrict__ bcnt,
                                                  float* __restrict__ dinv,
                                                  int2* __restrict__ rowinfo,
                                                  int* __restrict__ ticket) {
    __shared__ int h[NPB];
    __shared__ int tmp[256];
    __shared__ int base;
    int b = blockIdx.x, t = threadIdx.x;
    h[t] = 0;
    __syncthreads();
    int s0 = b * CAP, s1 = s0 + bcnt[b];
    for (int k = s0 + t; k < s1; k += 256) atomicAdd(&h[bedge[k].y & 255], 1);
    __syncthreads();
    int deg = h[t];
    int node = b * NPB + t;
    int pdeg = (deg + 7) & ~7;                    // pad to multiple of 8
    tmp[t] = pdeg;
    __syncthreads();
    for (int off = 1; off < 256; off <<= 1) {
        int uu = (t >= off) ? tmp[t - off] : 0;
        __syncthreads();
        tmp[t] += uu;
        __syncthreads();
    }
    if (t == 255) base = atomicAdd(ticket, tmp[255]);
    __syncthreads();
    if (node < NN) {
        dinv[node] = rsqrtf((float)(deg + 1));    // +1: self-loop
        rowinfo[node] = make_int2(base + tmp[t] - pdeg, pdeg);
    }
}

// Per-bucket scatter into padded CSR; coef = dinv[src] (L2-hot gather) * dinv[dst].
__global__ __launch_bounds__(256) void csr_scatter(const int2* __restrict__ bedge,
                                                   const int* __restrict__ bcnt,
                                                   const int2* __restrict__ rowinfo,
                                                   const float* __restrict__ dinv,
                                                   int2* __restrict__ csr_pair) {
    __shared__ int cur[NPB];
    __shared__ int rl[NPB];
    __shared__ float sdinv[NPB];
    int b = blockIdx.x, t = threadIdx.x;
    int node = b * NPB + t;
    rl[t] = (node < NN) ? rowinfo[node].x : 0;
    sdinv[t] = (node < NN) ? dinv[node] : 0.f;
    cur[t] = 0;
    __syncthreads();
    int s0 = b * CAP, s1 = s0 + bcnt[b];
    for (int k = s0 + t; k < s1; k += 256) {
        int2 eg = bedge[k];
        int li = eg.y & 255;
        int p = atomicAdd(&cur[li], 1);
        float coef = dinv[eg.x] * sdinv[li];
        csr_pair[rl[li] + p] = make_int2(eg.x, __float_as_int(coef));
    }
    __syncthreads();
    int dgc = cur[t];
    int pend = (dgc + 7) & ~7;
    int selfsrc = (node < NN) ? node : 0;
    for (int k = dgc; k < pend; ++k)
        csr_pair[rl[t] + k] = make_int2(selfsrc, 0);
}

// Pack W1 and W2 (f32 [k][n]) -> bf16 [n][k] in ONE launch.
__global__ void wt_pack2(const float* __restrict__ W1, const float* __restrict__ W2,
                         unsigned short* __restrict__ WT1, unsigned short* __restrict__ WT2) {
    int tid = blockIdx.x * 256 + threadIdx.x;
    const float* W = (tid < D * D) ? W1 : W2;
    unsigned short* WT = (tid < D * D) ? WT1 : WT2;
    int id = tid & (D * D - 1);
    int nn = id & 127, k = id >> 7;
    WT[nn * 128 + k] = f2bf(W[k * 128 + nn]);
}

// ---------------- MFMA GEMM1: hbf = bf16(x @ W1); A + W both LDS-staged ----------------
__global__ __launch_bounds__(256) void gemm_mfma(const float* __restrict__ A,
                                                 const unsigned short* __restrict__ WT,
                                                 unsigned short* __restrict__ out, int n) {
    __shared__ __align__(16) unsigned short a_lds[64 * 128];   // 16 KB
    __shared__ __align__(16) unsigned short w_lds[128 * 128];  // 32 KB
    int t = threadIdx.x;
    int m0 = blockIdx.x * 64;

    #pragma unroll
    for (int it = 0; it < 8; ++it) {
        int idx = it * 256 + t;
        int row = idx >> 4, c = idx & 15;
        uint4 v = *(const uint4*)&WT[row * 128 + c * 8];
        int byte = (row * 256 + c * 16) ^ ((row & 7) << 4);
        *(uint4*)((char*)w_lds + byte) = v;
    }
    #pragma unroll
    for (int it = 0; it < 4; ++it) {
        int idx = it * 256 + t;
        int row = idx >> 4, c = idx & 15;
        int grow = m0 + row;
        uint4 w = make_uint4(0u, 0u, 0u, 0u);
        if (grow < n) {
            float4 v0 = *(const float4*)&A[(size_t)grow * D + c * 8];
            float4 v1 = *(const float4*)&A[(size_t)grow * D + c * 8 + 4];
            w.x = (unsigned)f2bf(v0.x) | ((unsigned)f2bf(v0.y) << 16);
            w.y = (unsigned)f2bf(v0.z) | ((unsigned)f2bf(v0.w) << 16);
            w.z = (unsigned)f2bf(v1.x) | ((unsigned)f2bf(v1.y) << 16);
            w.w = (unsigned)f2bf(v1.z) | ((unsigned)f2bf(v1.w) << 16);
        }
        int byte = (row * 256 + c * 16) ^ ((row & 7) << 4);
        *(uint4*)((char*)a_lds + byte) = w;
    }
    __syncthreads();

    int wv = t >> 6, l = t & 63;
    int lrow = l & 15, lgrp = l >> 4;
    int arow = wv * 16 + lrow;

    f32x4 acc[8];
    #pragma unroll
    for (int nf = 0; nf < 8; ++nf) acc[nf] = (f32x4){0.f, 0.f, 0.f, 0.f};

    #pragma unroll
    for (int kk = 0; kk < 4; ++kk) {
        int abyte = (arow * 256 + kk * 64 + lgrp * 16) ^ ((arow & 7) << 4);
        bf16x8 afrag = *(bf16x8*)((char*)a_lds + abyte);
        #pragma unroll
        for (int nf = 0; nf < 8; ++nf) {
            int bcol = nf * 16 + lrow;
            int bbyte = (bcol * 256 + kk * 64 + lgrp * 16) ^ ((bcol & 7) << 4);
            bf16x8 bfrag = *(bf16x8*)((char*)w_lds + bbyte);
            acc[nf] = __builtin_amdgcn_mfma_f32_16x16x32_bf16(afrag, bfrag, acc[nf], 0, 0, 0);
        }
    }

    #pragma unroll
    for (int nf = 0; nf < 8; ++nf) {
        #pragma unroll
        for (int r = 0; r < 4; ++r) {
            int grow = m0 + wv * 16 + lgrp * 4 + r;
            if (grow < n) out[(size_t)grow * D + nf * 16 + lrow] = f2bf(acc[nf][r]);
        }
    }
}

// ---------------- aggregation helpers ----------------

// one 8-edge block: 4 nt pair-loads + 8 gathers + 16 fma
__device__ inline void agg8(const unsigned* __restrict__ h, const int2* __restrict__ csr_pair,
                            int e, int lane, float& accx, float& accy) {
    i32x4 q0 = __builtin_nontemporal_load((const i32x4*)(csr_pair + e + 0));
    i32x4 q1 = __builtin_nontemporal_load((const i32x4*)(csr_pair + e + 2));
    i32x4 q2 = __builtin_nontemporal_load((const i32x4*)(csr_pair + e + 4));
    i32x4 q3 = __builtin_nontemporal_load((const i32x4*)(csr_pair + e + 6));
    unsigned g0 = h[(size_t)q0[0] * (D / 2) + lane];
    unsigned g1 = h[(size_t)q0[2] * (D / 2) + lane];
    unsigned g2 = h[(size_t)q1[0] * (D / 2) + lane];
    unsigned g3 = h[(size_t)q1[2] * (D / 2) + lane];
    unsigned g4 = h[(size_t)q2[0] * (D / 2) + lane];
    unsigned g5 = h[(size_t)q2[2] * (D / 2) + lane];
    unsigned g6 = h[(size_t)q3[0] * (D / 2) + lane];
    unsigned g7 = h[(size_t)q3[2] * (D / 2) + lane];
    float ax, ay, c;
    c = __int_as_float(q0[1]); bf2x(g0, ax, ay); accx = fmaf(c, ax, accx); accy = fmaf(c, ay, accy);
    c = __int_as_float(q0[3]); bf2x(g1, ax, ay); accx = fmaf(c, ax, accx); accy = fmaf(c, ay, accy);
    c = __int_as_float(q1[1]); bf2x(g2, ax, ay); accx = fmaf(c, ax, accx); accy = fmaf(c, ay, accy);
    c = __int_as_float(q1[3]); bf2x(g3, ax, ay); accx = fmaf(c, ax, accx); accy = fmaf(c, ay, accy);
    c = __int_as_float(q2[1]); bf2x(g4, ax, ay); accx = fmaf(c, ax, accx); accy = fmaf(c, ay, accy);
    c = __int_as_float(q2[3]); bf2x(g5, ax, ay); accx = fmaf(c, ax, accx); accy = fmaf(c, ay, accy);
    c = __int_as_float(q3[1]); bf2x(g6, ax, ay); accx = fmaf(c, ax, accx); accy = fmaf(c, ay, accy);
    c = __int_as_float(q3[3]); bf2x(g7, ax, ay); accx = fmaf(c, ax, accx); accy = fmaf(c, ay, accy);
}

// joint 2-node 8+8 edge loop (16 gathers in flight), then drains
__device__ inline void agg_2node(const unsigned* __restrict__ h,
                                 const int2* __restrict__ csr_pair,
                                 int eA, int eA1, int eB, int eB1, int lane,
                                 float& aAx, float& aAy, float& aBx, float& aBy) {
    while (eA < eA1 && eB < eB1) {
        i32x4 qA0 = __builtin_nontemporal_load((const i32x4*)(csr_pair + eA + 0));
        i32x4 qA1 = __builtin_nontemporal_load((const i32x4*)(csr_pair + eA + 2));
        i32x4 qA2 = __builtin_nontemporal_load((const i32x4*)(csr_pair + eA + 4));
        i32x4 qA3 = __builtin_nontemporal_load((const i32x4*)(csr_pair + eA + 6));
        i32x4 qB0 = __builtin_nontemporal_load((const i32x4*)(csr_pair + eB + 0));
        i32x4 qB1 = __builtin_nontemporal_load((const i32x4*)(csr_pair + eB + 2));
        i32x4 qB2 = __builtin_nontemporal_load((const i32x4*)(csr_pair + eB + 4));
        i32x4 qB3 = __builtin_nontemporal_load((const i32x4*)(csr_pair + eB + 6));
        unsigned gA0 = h[(size_t)qA0[0] * (D / 2) + lane];
        unsigned gA1 = h[(size_t)qA0[2] * (D / 2) + lane];
        unsigned gA2 = h[(size_t)qA1[0] * (D / 2) + lane];
        unsigned gA3 = h[(size_t)qA1[2] * (D / 2) + lane];
        unsigned gA4 = h[(size_t)qA2[0] * (D / 2) + lane];
        unsigned gA5 = h[(size_t)qA2[2] * (D / 2) + lane];
        unsigned gA6 = h[(size_t)qA3[0] * (D / 2) + lane];
        unsigned gA7 = h[(size_t)qA3[2] * (D / 2) + lane];
        unsigned gB0 = h[(size_t)qB0[0] * (D / 2) + lane];
        unsigned gB1 = h[(size_t)qB0[2] * (D / 2) + lane];
        unsigned gB2 = h[(size_t)qB1[0] * (D / 2) + lane];
        unsigned gB3 = h[(size_t)qB1[2] * (D / 2) + lane];
        unsigned gB4 = h[(size_t)qB2[0] * (D / 2) + lane];
        unsigned gB5 = h[(size_t)qB2[2] * (D / 2) + lane];
        unsigned gB6 = h[(size_t)qB3[0] * (D / 2) + lane];
        unsigned gB7 = h[(size_t)qB3[2] * (D / 2) + lane];
        float ax, ay, c;
        c = __int_as_float(qA0[1]); bf2x(gA0, ax, ay); aAx = fmaf(c, ax, aAx); aAy = fmaf(c, ay, aAy);
        c = __int_as_float(qA0[3]); bf2x(gA1, ax, ay); aAx = fmaf(c, ax, aAx); aAy = fmaf(c, ay, aAy);
        c = __int_as_float(qA1[1]); bf2x(gA2, ax, ay); aAx = fmaf(c, ax, aAx); aAy = fmaf(c, ay, aAy);
        c = __int_as_float(qA1[3]); bf2x(gA3, ax, ay); aAx = fmaf(c, ax, aAx); aAy = fmaf(c, ay, aAy);
        c = __int_as_float(qA2[1]); bf2x(gA4, ax, ay); aAx = fmaf(c, ax, aAx); aAy = fmaf(c, ay, aAy);
        c = __int_as_float(qA2[3]); bf2x(gA5, ax, ay); aAx = fmaf(c, ax, aAx); aAy = fmaf(c, ay, aAy);
        c = __int_as_float(qA3[1]); bf2x(gA6, ax, ay); aAx = fmaf(c, ax, aAx); aAy = fmaf(c, ay, aAy);
        c = __int_as_float(qA3[3]); bf2x(gA7, ax, ay); aAx = fmaf(c, ax, aAx); aAy = fmaf(c, ay, aAy);
        c = __int_as_float(qB0[1]); bf2x(gB0, ax, ay); aBx = fmaf(c, ax, aBx); aBy = fmaf(c, ay, aBy);
        c = __int_as_float(qB0[3]); bf2x(gB1, ax, ay); aBx = fmaf(c, ax, aBx); aBy = fmaf(c, ay, aBy);
        c = __int_as_float(qB1[1]); bf2x(gB2, ax, ay); aBx = fmaf(c, ax, aBx); aBy = fmaf(c, ay, aBy);
        c = __int_as_float(qB1[3]); bf2x(gB3, ax, ay); aBx = fmaf(c, ax, aBx); aBy = fmaf(c, ay, aBy);
        c = __int_as_float(qB2[1]); bf2x(gB4, ax, ay); aBx = fmaf(c, ax, aBx); aBy = fmaf(c, ay, aBy);
        c = __int_as_float(qB2[3]); bf2x(gB5, ax, ay); aBx = fmaf(c, ax, aBx); aBy = fmaf(c, ay, aBy);
        c = __int_as_float(qB3[1]); bf2x(gB6, ax, ay); aBx = fmaf(c, ax, aBx); aBy = fmaf(c, ay, aBy);
        c = __int_as_float(qB3[3]); bf2x(gB7, ax, ay); aBx = fmaf(c, ax, aBx); aBy = fmaf(c, ay, aBy);
        eA += 8; eB += 8;
    }
    while (eA < eA1) { agg8(h, csr_pair, eA, lane, aAx, aAy); eA += 8; }
    while (eB < eB1) { agg8(h, csr_pair, eB, lane, aBx, aBy); eB += 8; }
}

// ---------------- layer 1: agg + bias + leaky + residual + LN1 + GEMM2 (fused MFMA) ----------------
__global__ __launch_bounds__(512) void agg_ln1_gemm(const unsigned* __restrict__ h,
                                                    const float* __restrict__ x,
                                                    const float* __restrict__ bias,
                                                    const float* __restrict__ gamma,
                                                    const float* __restrict__ beta,
                                                    const float* __restrict__ dinv,
                                                    const int2* __restrict__ rowinfo,
                                                    const int2* __restrict__ csr_pair,
                                                    const unsigned short* __restrict__ wt2,
                                                    unsigned short* __restrict__ hbf2) {
    __shared__ __align__(16) unsigned short w_lds[128 * 128];  // 32 KB
    __shared__ __align__(16) unsigned short a_lds[16 * 128];   // 4 KB
    int t = threadIdx.x;

    #pragma unroll
    for (int it = 0; it < 4; ++it) {
        int idx = it * 512 + t;
        int row = idx >> 4, c = idx & 15;
        uint4 v = *(const uint4*)&wt2[row * 128 + c * 8];
        int byte = (row * 256 + c * 16) ^ ((row & 7) << 4);
        *(uint4*)((char*)w_lds + byte) = v;
    }

    int wid = t >> 6, lane = t & 63;
    int iA = blockIdx.x * 16 + wid * 2;   // NN = 50000 = 3125 * 16, exact
    int iB = iA + 1;
    float diA = dinv[iA], diB = dinv[iB];

    float hx, hy;
    bf2x(h[(size_t)iA * (D / 2) + lane], hx, hy);
    float aAx = diA * diA * hx, aAy = diA * diA * hy;
    bf2x(h[(size_t)iB * (D / 2) + lane], hx, hy);
    float aBx = diB * diB * hx, aBy = diB * diB * hy;

    int2 riA = rowinfo[iA];
    int2 riB = rowinfo[iB];
    int eA = __builtin_amdgcn_readfirstlane(riA.x);
    int eA1 = eA + __builtin_amdgcn_readfirstlane(riA.y);
    int eB = __builtin_amdgcn_readfirstlane(riB.x);
    int eB1 = eB + __builtin_amdgcn_readfirstlane(riB.y);
    agg_2node(h, csr_pair, eA, eA1, eB, eB1, lane, aAx, aAy, aBx, aBy);

    float2 bv = *(const float2*)&bias[2 * lane];
    float2 gv = *(const float2*)&gamma[2 * lane];
    float2 bt = *(const float2*)&beta[2 * lane];

    aAx += bv.x; aAy += bv.y;
    aBx += bv.x; aBy += bv.y;
    aAx = aAx > 0.f ? aAx : NEG_SLOPE * aAx;
    aAy = aAy > 0.f ? aAy : NEG_SLOPE * aAy;
    aBx = aBx > 0.f ? aBx : NEG_SLOPE * aBx;
    aBy = aBy > 0.f ? aBy : NEG_SLOPE * aBy;

    size_t rowA = (size_t)iA * D + 2 * lane;
    size_t rowB = (size_t)iB * D + 2 * lane;
    float2 xA = *(const float2*)&x[rowA];
    float2 xB = *(const float2*)&x[rowB];
    float vA0 = aAx + xA.x, vA1 = aAy + xA.y;
    float vB0 = aBx + xB.x, vB1 = aBy + xB.y;

    float sA1 = vA0 + vA1, sA2 = vA0 * vA0 + vA1 * vA1;
    float sB1 = vB0 + vB1, sB2 = vB0 * vB0 + vB1 * vB1;
    #pragma unroll
    for (int off = 1; off < 64; off <<= 1) {
        sA1 += __shfl_xor(sA1, off, 64);
        sA2 += __shfl_xor(sA2, off, 64);
        sB1 += __shfl_xor(sB1, off, 64);
        sB2 += __shfl_xor(sB2, off, 64);
    }
    float muA = sA1 * (1.f / 128.f);
    float varA = fmaxf(sA2 * (1.f / 128.f) - muA * muA, 0.f);
    float rsA = rsqrtf(varA + LN_EPS);
    float muB = sB1 * (1.f / 128.f);
    float varB = fmaxf(sB2 * (1.f / 128.f) - muB * muB, 0.f);
    float rsB = rsqrtf(varB + LN_EPS);

    float oA0 = (vA0 - muA) * rsA * gv.x + bt.x;
    float oA1 = (vA1 - muA) * rsA * gv.y + bt.y;
    float oB0 = (vB0 - muB) * rsB * gv.x + bt.x;
    float oB1 = (vB1 - muB) * rsB * gv.y + bt.y;

    int rA = wid * 2, rB = wid * 2 + 1;
    unsigned dwA = (unsigned)f2bf(oA0) | ((unsigned)f2bf(oA1) << 16);
    unsigned dwB = (unsigned)f2bf(oB0) | ((unsigned)f2bf(oB1) << 16);
    int byteA = (rA * 256 + lane * 4) ^ ((rA & 7) << 4);
    int byteB = (rB * 256 + lane * 4) ^ ((rB & 7) << 4);
    *(unsigned*)((char*)a_lds + byteA) = dwA;
    *(unsigned*)((char*)a_lds + byteB) = dwB;
    __syncthreads();

    int lrow = lane & 15, lgrp = lane >> 4;
    f32x4 acc = (f32x4){0.f, 0.f, 0.f, 0.f};
    #pragma unroll
    for (int kk = 0; kk < 4; ++kk) {
        int abyte = (lrow * 256 + kk * 64 + lgrp * 16) ^ ((lrow & 7) << 4);
        bf16x8 afrag = *(bf16x8*)((char*)a_lds + abyte);
        int bcol = wid * 16 + lrow;
        int bbyte = (bcol * 256 + kk * 64 + lgrp * 16) ^ ((bcol & 7) << 4);
        bf16x8 bfrag = *(bf16x8*)((char*)w_lds + bbyte);
        acc = __builtin_amdgcn_mfma_f32_16x16x32_bf16(afrag, bfrag, acc, 0, 0, 0);
    }
    #pragma unroll
    for (int r = 0; r < 4; ++r) {
        int grow = blockIdx.x * 16 + lgrp * 4 + r;
        hbf2[(size_t)grow * D + wid * 16 + lrow] = f2bf(acc[r]);
    }
}

// ---------------- layer 2: agg + bias + residual + LN2 + leaky (final f32 out) ----------------
__global__ __launch_bounds__(256) void agg_ln2(const unsigned* __restrict__ h,
                                               const float* __restrict__ x,
                                               const float* __restrict__ bias,
                                               const float* __restrict__ gamma,
                                               const float* __restrict__ beta,
                                               const float* __restrict__ dinv,
                                               const int2* __restrict__ rowinfo,
                                               const int2* __restrict__ csr_pair,
                                               float* __restrict__ out) {
    int wid = threadIdx.x >> 6;
    int lane = threadIdx.x & 63;
    int iA = blockIdx.x * 8 + wid * 2;   // NN = 50000 = 6250 * 8, exact
    int iB = iA + 1;
    float diA = dinv[iA], diB = dinv[iB];

    float hx, hy;
    bf2x(h[(size_t)iA * (D / 2) + lane], hx, hy);
    float aAx = diA * diA * hx, aAy = diA * diA * hy;
    bf2x(h[(size_t)iB * (D / 2) + lane], hx, hy);
    float aBx = diB * diB * hx, aBy = diB * diB * hy;

    int2 riA = rowinfo[iA];
    int2 riB = rowinfo[iB];
    int eA = __builtin_amdgcn_readfirstlane(riA.x);
    int eA1 = eA + __builtin_amdgcn_readfirstlane(riA.y);
    int eB = __builtin_amdgcn_readfirstlane(riB.x);
    int eB1 = eB + __builtin_amdgcn_readfirstlane(riB.y);
    agg_2node(h, csr_pair, eA, eA1, eB, eB1, lane, aAx, aAy, aBx, aBy);

    float2 bv = *(const float2*)&bias[2 * lane];
    float2 gv = *(const float2*)&gamma[2 * lane];
    float2 bt = *(const float2*)&beta[2 * lane];

    aAx += bv.x; aAy += bv.y;
    aBx += bv.x; aBy += bv.y;
    size_t rowA = (size_t)iA * D + 2 * lane;
    size_t rowB = (size_t)iB * D + 2 * lane;
    float2 xA = *(const float2*)&x[rowA];
    float2 xB = *(const float2*)&x[rowB];
    float vA0 = aAx + xA.x, vA1 = aAy + xA.y;
    float vB0 = aBx + xB.x, vB1 = aBy + xB.y;

    float sA1 = vA0 + vA1, sA2 = vA0 * vA0 + vA1 * vA1;
    float sB1 = vB0 + vB1, sB2 = vB0 * vB0 + vB1 * vB1;
    #pragma unroll
    for (int off = 1; off < 64; off <<= 1) {
        sA1 += __shfl_xor(sA1, off, 64);
        sA2 += __shfl_xor(sA2, off, 64);
        sB1 += __shfl_xor(sB1, off, 64);
        sB2 += __shfl_xor(sB2, off, 64);
    }
    float muA = sA1 * (1.f / 128.f);
    float varA = fmaxf(sA2 * (1.f / 128.f) - muA * muA, 0.f);
    float rsA = rsqrtf(varA + LN_EPS);
    float muB = sB1 * (1.f / 128.f);
    float varB = fmaxf(sB2 * (1.f / 128.f) - muB * muB, 0.f);
    float rsB = rsqrtf(varB + LN_EPS);

    float oA0 = (vA0 - muA) * rsA * gv.x + bt.x;
    float oA1 = (vA1 - muA) * rsA * gv.y + bt.y;
    float oB0 = (vB0 - muB) * rsB * gv.x + bt.x;
    float oB1 = (vB1 - muB) * rsB * gv.y + bt.y;
    oA0 = oA0 > 0.f ? oA0 : NEG_SLOPE * oA0;
    oA1 = oA1 > 0.f ? oA1 : NEG_SLOPE * oA1;
    oB0 = oB0 > 0.f ? oB0 : NEG_SLOPE * oB0;
    oB1 = oB1 > 0.f ? oB1 : NEG_SLOPE * oB1;
    *(float2*)&out[rowA] = make_float2(oA0, oA1);
    *(float2*)&out[rowB] = make_float2(oB0, oB1);
}

extern "C" void kernel_launch(void* const* d_in, const int* in_sizes, int n_in,
                              void* d_out, int out_size, void* d_ws, size_t ws_size,
                              hipStream_t stream) {
    const float* x    = (const float*)d_in[0];
    const int*   ei   = (const int*)d_in[1];   // [2, NE]: row0 src, row1 dst
    const float* W1   = (const float*)d_in[2];
    const float* b1   = (const float*)d_in[3];
    const float* ln1g = (const float*)d_in[4];
    const float* ln1b = (const float*)d_in[5];
    const float* W2   = (const float*)d_in[6];
    const float* b2   = (const float*)d_in[7];
    const float* ln2g = (const float*)d_in[8];
    const float* ln2b = (const float*)d_in[9];
    float* out = (float*)d_out;

    const int* srcp = ei;
    const int* dstp = ei + NE;

    char* ws = (char*)d_ws;
    size_t p = 0;
    auto alloc = [&](size_t bytes) {
        char* r = ws + p;
        p += (bytes + 255) & ~(size_t)255;
        return r;
    };
    int*   bcursor  = (int*)alloc((NB + 1) * 4);         // [NB] = ticket
    int2*  rowinfo  = (int2*)alloc((size_t)NN * 8);
    float* dinv     = (float*)alloc(NN * 4);
    int2*  bedge    = (int2*)alloc((size_t)NB * CAP * 8);
    int2*  csr_pair = (int2*)alloc(((size_t)NE + 8 * NN) * 8);  // padded CSR
    unsigned short* hbf  = (unsigned short*)alloc((size_t)NN * D * 2);
    unsigned short* hbf2 = (unsigned short*)alloc((size_t)NN * D * 2);
    unsigned short* wt1  = (unsigned short*)alloc(D * D * 2);
    unsigned short* wt2  = (unsigned short*)alloc(D * D * 2);

    hipMemsetAsync(bcursor, 0, (NB + 1) * 4, stream);

    wt_pack2<<<2 * D * D / 256, 256, 0, stream>>>(W1, W2, wt1, wt2);

    // CSR chain + GEMM1, each at full occupancy
    bucket_scatter<<<NCH, 256, 0, stream>>>(srcp, dstp, bcursor, bedge);
    gemm_mfma<<<(NN + 63) / 64, 256, 0, stream>>>(x, wt1, hbf, NN);
    node_count<<<NB, 256, 0, stream>>>(bedge, bcursor, dinv, rowinfo, &bcursor[NB]);
    csr_scatter<<<NB, 256, 0, stream>>>(bedge, bcursor, rowinfo, dinv, csr_pair);

    // Layer 1 (+ fused GEMM2): hbf2 = bf16( LN1(leaky(agg(hbf)+b1)+x) @ W2 )
    agg_ln1_gemm<<<NN / 16, 512, 0, stream>>>((const unsigned*)hbf, x, b1, ln1g, ln1b,
                                              dinv, rowinfo, csr_pair, wt2, hbf2);

    // Layer 2: out = leaky(LN2(agg(hbf2)+b2+x))
    agg_ln2<<<NN / 8, 256, 0, stream>>>((const unsigned*)hbf2, x, b2, ln2g, ln2b,
                                        dinv, rowinfo, csr_pair, out);
}

// Round 12
// 130.099 us; speedup vs baseline: 1.1513x; 1.0277x over previous
//
#include <hip/hip_runtime.h>
#include <hip/hip_bf16.h>

#define NN 50000
#define NE 800000
#define D 128
#define NEG_SLOPE 0.01f
#define LN_EPS 1e-5f

#define NPB 256                 // nodes per bucket (bucket = dst >> 8)
#define NB 196                  // ceil(NN / NPB); NB*256 = 50176
#define CAP 6144                // per-bucket bedge capacity (avg 4082, max ~4340)
#define ECH 8192                // edges per bucket-workgroup
#define NCH ((NE + ECH - 1) / ECH)  // 98

typedef __attribute__((ext_vector_type(8))) short bf16x8;
typedef __attribute__((ext_vector_type(4))) float f32x4;
typedef __attribute__((ext_vector_type(4))) int i32x4;

// f32 -> bf16 round-to-nearest-even (finite values)
__device__ inline unsigned short f2bf(float f) {
    unsigned u = __float_as_uint(f);
    unsigned r = 0x7FFFu + ((u >> 16) & 1u);
    return (unsigned short)((u + r) >> 16);
}
// unpack one dword = 2 bf16 -> 2 floats
__device__ inline void bf2x(unsigned u, float& lo, float& hi) {
    lo = __uint_as_float(u << 16);
    hi = __uint_as_float(u & 0xFFFF0000u);
}

// ---------------- CSR build ----------------

// Direct bucket scatter: LDS hist -> reserve global run -> direct global writes.
__global__ __launch_bounds__(256) void bucket_scatter(const int* __restrict__ src,
                                                      const int* __restrict__ dst,
                                                      int* __restrict__ bcursor,
                                                      int2* __restrict__ bedge) {
    __shared__ int hist[NB], lcur[NB], gbase[NB];
    int t = threadIdx.x;
    int e0 = blockIdx.x * ECH;
    int ecnt = min(ECH, NE - e0);
    if (t < NB) hist[t] = 0;
    __syncthreads();
    for (int k = t; k < ecnt; k += 256) atomicAdd(&hist[dst[e0 + k] >> 8], 1);
    __syncthreads();
    if (t < NB) {
        gbase[t] = atomicAdd(&bcursor[t], hist[t]);   // reserve exclusive run
        lcur[t] = 0;
    }
    __syncthreads();
    for (int k = t; k < ecnt; k += 256) {
        int s = src[e0 + k], d = dst[e0 + k];
        int b = d >> 8;
        int p = atomicAdd(&lcur[b], 1);
        bedge[(size_t)b * CAP + gbase[b] + p] = make_int2(s, d);
    }
}

// Per-bucket node histogram from bedge -> dinv + rowinfo (padded run via ticket).
__global__ __launch_bounds__(256) void node_count(const int2* __restrict__ bedge,
                                                  const int* __restrict__ bcnt,
                                                  float* __restrict__ dinv,
                                                  int2* __restrict__ rowinfo,
                                                  int* __restrict__ ticket) {
    __shared__ int h[NPB];
    __shared__ int tmp[256];
    __shared__ int base;
    int b = blockIdx.x, t = threadIdx.x;
    h[t] = 0;
    __syncthreads();
    int s0 = b * CAP, s1 = s0 + bcnt[b];
    for (int k = s0 + t; k < s1; k += 256) atomicAdd(&h[bedge[k].y & 255], 1);
    __syncthreads();
    int deg = h[t];
    int node = b * NPB + t;
    int pdeg = (deg + 7) & ~7;                    // pad to multiple of 8
    tmp[t] = pdeg;
    __syncthreads();
    for (int off = 1; off < 256; off <<= 1) {
        int uu = (t >= off) ? tmp[t - off] : 0;
        __syncthreads();
        tmp[t] += uu;
        __syncthreads();
    }
    if (t == 255) base = atomicAdd(ticket, tmp[255]);
    __syncthreads();
    if (node < NN) {
        dinv[node] = rsqrtf((float)(deg + 1));    // +1: self-loop
        rowinfo[node] = make_int2(base + tmp[t] - pdeg, pdeg);
    }
}

// Per-bucket scatter into padded CSR (bare src index, 4 B/edge).
// Pad entries point at the zero row (index NN) -> contribute 0 to the sum.
__global__ __launch_bounds__(256) void csr_scatter(const int2* __restrict__ bedge,
                                                   const int* __restrict__ bcnt,
                                                   const int2* __restrict__ rowinfo,
                                                   int* __restrict__ csr_src) {
    __shared__ int cur[NPB];
    __shared__ int rl[NPB];
    int b = blockIdx.x, t = threadIdx.x;
    int node = b * NPB + t;
    rl[t] = (node < NN) ? rowinfo[node].x : 0;
    cur[t] = 0;
    __syncthreads();
    int s0 = b * CAP, s1 = s0 + bcnt[b];
    for (int k = s0 + t; k < s1; k += 256) {
        int2 eg = bedge[k];
        int li = eg.y & 255;
        int p = atomicAdd(&cur[li], 1);
        csr_src[rl[li] + p] = eg.x;
    }
    __syncthreads();
    int dgc = cur[t];
    int pend = (dgc + 7) & ~7;
    for (int k = dgc; k < pend; ++k)
        csr_src[rl[t] + k] = NN;                  // zero-row pad
}

// Pack W1,W2 (f32 [k][n]) -> bf16 [n][k]; also zero the pad rows of hbf/hbf2.
__global__ void wt_pack2(const float* __restrict__ W1, const float* __restrict__ W2,
                         unsigned short* __restrict__ WT1, unsigned short* __restrict__ WT2,
                         unsigned short* __restrict__ hbf, unsigned short* __restrict__ hbf2) {
    int tid = blockIdx.x * 256 + threadIdx.x;
    if (tid < 32) {
        uint4 z = make_uint4(0u, 0u, 0u, 0u);
        if (tid < 16) *(uint4*)&hbf[(size_t)NN * D + tid * 8] = z;
        else          *(uint4*)&hbf2[(size_t)NN * D + (tid - 16) * 8] = z;
    }
    const float* W = (tid < D * D) ? W1 : W2;
    unsigned short* WT = (tid < D * D) ? WT1 : WT2;
    int id = tid & (D * D - 1);
    int nn = id & 127, k = id >> 7;
    WT[nn * 128 + k] = f2bf(W[k * 128 + nn]);
}

// ---------------- MFMA GEMM1: hbf = bf16( dinv ⊙ (x @ W1) ) ----------------
__global__ __launch_bounds__(256) void gemm_mfma(const float* __restrict__ A,
                                                 const unsigned short* __restrict__ WT,
                                                 const float* __restrict__ dinv,
                                                 unsigned short* __restrict__ out, int n) {
    __shared__ __align__(16) unsigned short a_lds[64 * 128];   // 16 KB
    __shared__ __align__(16) unsigned short w_lds[128 * 128];  // 32 KB
    int t = threadIdx.x;
    int m0 = blockIdx.x * 64;

    #pragma unroll
    for (int it = 0; it < 8; ++it) {
        int idx = it * 256 + t;
        int row = idx >> 4, c = idx & 15;
        uint4 v = *(const uint4*)&WT[row * 128 + c * 8];
        int byte = (row * 256 + c * 16) ^ ((row & 7) << 4);
        *(uint4*)((char*)w_lds + byte) = v;
    }
    #pragma unroll
    for (int it = 0; it < 4; ++it) {
        int idx = it * 256 + t;
        int row = idx >> 4, c = idx & 15;
        int grow = m0 + row;
        uint4 w = make_uint4(0u, 0u, 0u, 0u);
        if (grow < n) {
            float4 v0 = *(const float4*)&A[(size_t)grow * D + c * 8];
            float4 v1 = *(const float4*)&A[(size_t)grow * D + c * 8 + 4];
            w.x = (unsigned)f2bf(v0.x) | ((unsigned)f2bf(v0.y) << 16);
            w.y = (unsigned)f2bf(v0.z) | ((unsigned)f2bf(v0.w) << 16);
            w.z = (unsigned)f2bf(v1.x) | ((unsigned)f2bf(v1.y) << 16);
            w.w = (unsigned)f2bf(v1.z) | ((unsigned)f2bf(v1.w) << 16);
        }
        int byte = (row * 256 + c * 16) ^ ((row & 7) << 4);
        *(uint4*)((char*)a_lds + byte) = w;
    }
    __syncthreads();

    int wv = t >> 6, l = t & 63;
    int lrow = l & 15, lgrp = l >> 4;
    int arow = wv * 16 + lrow;

    f32x4 acc[8];
    #pragma unroll
    for (int nf = 0; nf < 8; ++nf) acc[nf] = (f32x4){0.f, 0.f, 0.f, 0.f};

    #pragma unroll
    for (int kk = 0; kk < 4; ++kk) {
        int abyte = (arow * 256 + kk * 64 + lgrp * 16) ^ ((arow & 7) << 4);
        bf16x8 afrag = *(bf16x8*)((char*)a_lds + abyte);
        #pragma unroll
        for (int nf = 0; nf < 8; ++nf) {
            int bcol = nf * 16 + lrow;
            int bbyte = (bcol * 256 + kk * 64 + lgrp * 16) ^ ((bcol & 7) << 4);
            bf16x8 bfrag = *(bf16x8*)((char*)w_lds + bbyte);
            acc[nf] = __builtin_amdgcn_mfma_f32_16x16x32_bf16(afrag, bfrag, acc[nf], 0, 0, 0);
        }
    }

    #pragma unroll
    for (int r = 0; r < 4; ++r) {
        int grow = m0 + wv * 16 + lgrp * 4 + r;
        if (grow < n) {
            float dv = dinv[grow];
            #pragma unroll
            for (int nf = 0; nf < 8; ++nf)
                out[(size_t)grow * D + nf * 16 + lrow] = f2bf(dv * acc[nf][r]);
        }
    }
}

// ---------------- aggregation helpers (coef-free: pure adds) ----------------

// one node, 8 edges: 2 nt int4 loads + 8 gathers + 16 adds
__device__ inline void agg8s(const unsigned* __restrict__ h, const int* __restrict__ csr,
                             int e, int lane, float& ax_, float& ay_) {
    i32x4 s0 = __builtin_nontemporal_load((const i32x4*)(csr + e));
    i32x4 s1 = __builtin_nontemporal_load((const i32x4*)(csr + e + 4));
    unsigned g0 = h[(size_t)s0[0] * (D / 2) + lane];
    unsigned g1 = h[(size_t)s0[1] * (D / 2) + lane];
    unsigned g2 = h[(size_t)s0[2] * (D / 2) + lane];
    unsigned g3 = h[(size_t)s0[3] * (D / 2) + lane];
    unsigned g4 = h[(size_t)s1[0] * (D / 2) + lane];
    unsigned g5 = h[(size_t)s1[1] * (D / 2) + lane];
    unsigned g6 = h[(size_t)s1[2] * (D / 2) + lane];
    unsigned g7 = h[(size_t)s1[3] * (D / 2) + lane];
    float lo, hi;
    bf2x(g0, lo, hi); ax_ += lo; ay_ += hi;
    bf2x(g1, lo, hi); ax_ += lo; ay_ += hi;
    bf2x(g2, lo, hi); ax_ += lo; ay_ += hi;
    bf2x(g3, lo, hi); ax_ += lo; ay_ += hi;
    bf2x(g4, lo, hi); ax_ += lo; ay_ += hi;
    bf2x(g5, lo, hi); ax_ += lo; ay_ += hi;
    bf2x(g6, lo, hi); ax_ += lo; ay_ += hi;
    bf2x(g7, lo, hi); ax_ += lo; ay_ += hi;
}

// joint 2-node loop: 16-deep per node (32 gathers in flight), then 8-deep drains
__device__ inline void agg_2node(const unsigned* __restrict__ h,
                                 const int* __restrict__ csr,
                                 int eA, int eA1, int eB, int eB1, int lane,
                                 float& aAx, float& aAy, float& aBx, float& aBy) {
    while (eA + 16 <= eA1 && eB + 16 <= eB1) {
        i32x4 sA0 = __builtin_nontemporal_load((const i32x4*)(csr + eA));
        i32x4 sA1 = __builtin_nontemporal_load((const i32x4*)(csr + eA + 4));
        i32x4 sA2 = __builtin_nontemporal_load((const i32x4*)(csr + eA + 8));
        i32x4 sA3 = __builtin_nontemporal_load((const i32x4*)(csr + eA + 12));
        i32x4 sB0 = __builtin_nontemporal_load((const i32x4*)(csr + eB));
        i32x4 sB1 = __builtin_nontemporal_load((const i32x4*)(csr + eB + 4));
        i32x4 sB2 = __builtin_nontemporal_load((const i32x4*)(csr + eB + 8));
        i32x4 sB3 = __builtin_nontemporal_load((const i32x4*)(csr + eB + 12));
        unsigned gA0 = h[(size_t)sA0[0] * (D / 2) + lane];
        unsigned gA1 = h[(size_t)sA0[1] * (D / 2) + lane];
        unsigned gA2 = h[(size_t)sA0[2] * (D / 2) + lane];
        unsigned gA3 = h[(size_t)sA0[3] * (D / 2) + lane];
        unsigned gA4 = h[(size_t)sA1[0] * (D / 2) + lane];
        unsigned gA5 = h[(size_t)sA1[1] * (D / 2) + lane];
        unsigned gA6 = h[(size_t)sA1[2] * (D / 2) + lane];
        unsigned gA7 = h[(size_t)sA1[3] * (D / 2) + lane];
        unsigned gA8 = h[(size_t)sA2[0] * (D / 2) + lane];
        unsigned gA9 = h[(size_t)sA2[1] * (D / 2) + lane];
        unsigned gAa = h[(size_t)sA2[2] * (D / 2) + lane];
        unsigned gAb = h[(size_t)sA2[3] * (D / 2) + lane];
        unsigned gAc = h[(size_t)sA3[0] * (D / 2) + lane];
        unsigned gAd = h[(size_t)sA3[1] * (D / 2) + lane];
        unsigned gAe = h[(size_t)sA3[2] * (D / 2) + lane];
        unsigned gAf = h[(size_t)sA3[3] * (D / 2) + lane];
        unsigned gB0 = h[(size_t)sB0[0] * (D / 2) + lane];
        unsigned gB1 = h[(size_t)sB0[1] * (D / 2) + lane];
        unsigned gB2 = h[(size_t)sB0[2] * (D / 2) + lane];
        unsigned gB3 = h[(size_t)sB0[3] * (D / 2) + lane];
        unsigned gB4 = h[(size_t)sB1[0] * (D / 2) + lane];
        unsigned gB5 = h[(size_t)sB1[1] * (D / 2) + lane];
        unsigned gB6 = h[(size_t)sB1[2] * (D / 2) + lane];
        unsigned gB7 = h[(size_t)sB1[3] * (D / 2) + lane];
        unsigned gB8 = h[(size_t)sB2[0] * (D / 2) + lane];
        unsigned gB9 = h[(size_t)sB2[1] * (D / 2) + lane];
        unsigned gBa = h[(size_t)sB2[2] * (D / 2) + lane];
        unsigned gBb = h[(size_t)sB2[3] * (D / 2) + lane];
        unsigned gBc = h[(size_t)sB3[0] * (D / 2) + lane];
        unsigned gBd = h[(size_t)sB3[1] * (D / 2) + lane];
        unsigned gBe = h[(size_t)sB3[2] * (D / 2) + lane];
        unsigned gBf = h[(size_t)sB3[3] * (D / 2) + lane];
        float lo, hi;
        bf2x(gA0, lo, hi); aAx += lo; aAy += hi;
        bf2x(gA1, lo, hi); aAx += lo; aAy += hi;
        bf2x(gA2, lo, hi); aAx += lo; aAy += hi;
        bf2x(gA3, lo, hi); aAx += lo; aAy += hi;
        bf2x(gA4, lo, hi); aAx += lo; aAy += hi;
        bf2x(gA5, lo, hi); aAx += lo; aAy += hi;
        bf2x(gA6, lo, hi); aAx += lo; aAy += hi;
        bf2x(gA7, lo, hi); aAx += lo; aAy += hi;
        bf2x(gA8, lo, hi); aAx += lo; aAy += hi;
        bf2x(gA9, lo, hi); aAx += lo; aAy += hi;
        bf2x(gAa, lo, hi); aAx += lo; aAy += hi;
        bf2x(gAb, lo, hi); aAx += lo; aAy += hi;
        bf2x(gAc, lo, hi); aAx += lo; aAy += hi;
        bf2x(gAd, lo, hi); aAx += lo; aAy += hi;
        bf2x(gAe, lo, hi); aAx += lo; aAy += hi;
        bf2x(gAf, lo, hi); aAx += lo; aAy += hi;
        bf2x(gB0, lo, hi); aBx += lo; aBy += hi;
        bf2x(gB1, lo, hi); aBx += lo; aBy += hi;
        bf2x(gB2, lo, hi); aBx += lo; aBy += hi;
        bf2x(gB3, lo, hi); aBx += lo; aBy += hi;
        bf2x(gB4, lo, hi); aBx += lo; aBy += hi;
        bf2x(gB5, lo, hi); aBx += lo; aBy += hi;
        bf2x(gB6, lo, hi); aBx += lo; aBy += hi;
        bf2x(gB7, lo, hi); aBx += lo; aBy += hi;
        bf2x(gB8, lo, hi); aBx += lo; aBy += hi;
        bf2x(gB9, lo, hi); aBx += lo; aBy += hi;
        bf2x(gBa, lo, hi); aBx += lo; aBy += hi;
        bf2x(gBb, lo, hi); aBx += lo; aBy += hi;
        bf2x(gBc, lo, hi); aBx += lo; aBy += hi;
        bf2x(gBd, lo, hi); aBx += lo; aBy += hi;
        bf2x(gBe, lo, hi); aBx += lo; aBy += hi;
        bf2x(gBf, lo, hi); aBx += lo; aBy += hi;
        eA += 16; eB += 16;
    }
    while (eA + 8 <= eA1 && eB + 8 <= eB1) {
        agg8s(h, csr, eA, lane, aAx, aAy);
        agg8s(h, csr, eB, lane, aBx, aBy);
        eA += 8; eB += 8;
    }
    while (eA < eA1) { agg8s(h, csr, eA, lane, aAx, aAy); eA += 8; }
    while (eB < eB1) { agg8s(h, csr, eB, lane, aBx, aBy); eB += 8; }
}

// ---------------- layer 1: agg + bias + leaky + residual + LN1 + GEMM2 (fused MFMA) ----------------
// hbf2 = dinv ⊙ ( LN1(...) @ W2 ), bf16
__global__ __launch_bounds__(512) void agg_ln1_gemm(const unsigned* __restrict__ h,
                                                    const float* __restrict__ x,
                                                    const float* __restrict__ bias,
                                                    const float* __restrict__ gamma,
                                                    const float* __restrict__ beta,
                                                    const float* __restrict__ dinv,
                                                    const int2* __restrict__ rowinfo,
                                                    const int* __restrict__ csr_src,
                                                    const unsigned short* __restrict__ wt2,
                                                    unsigned short* __restrict__ hbf2) {
    __shared__ __align__(16) unsigned short w_lds[128 * 128];  // 32 KB
    __shared__ __align__(16) unsigned short a_lds[16 * 128];   // 4 KB
    int t = threadIdx.x;

    #pragma unroll
    for (int it = 0; it < 4; ++it) {
        int idx = it * 512 + t;
        int row = idx >> 4, c = idx & 15;
        uint4 v = *(const uint4*)&wt2[row * 128 + c * 8];
        int byte = (row * 256 + c * 16) ^ ((row & 7) << 4);
        *(uint4*)((char*)w_lds + byte) = v;
    }

    int wid = t >> 6, lane = t & 63;
    int iA = blockIdx.x * 16 + wid * 2;   // NN = 50000 = 3125 * 16, exact
    int iB = iA + 1;
    float diA = dinv[iA], diB = dinv[iB];

    // acc starts with self term h'[i]; final agg = dinv_i * acc
    float aAx, aAy, aBx, aBy;
    bf2x(h[(size_t)iA * (D / 2) + lane], aAx, aAy);
    bf2x(h[(size_t)iB * (D / 2) + lane], aBx, aBy);

    int2 riA = rowinfo[iA];
    int2 riB = rowinfo[iB];
    int eA = __builtin_amdgcn_readfirstlane(riA.x);
    int eA1 = eA + __builtin_amdgcn_readfirstlane(riA.y);
    int eB = __builtin_amdgcn_readfirstlane(riB.x);
    int eB1 = eB + __builtin_amdgcn_readfirstlane(riB.y);
    agg_2node(h, csr_src, eA, eA1, eB, eB1, lane, aAx, aAy, aBx, aBy);

    float2 bv = *(const float2*)&bias[2 * lane];
    float2 gv = *(const float2*)&gamma[2 * lane];
    float2 bt = *(const float2*)&beta[2 * lane];

    aAx = fmaf(diA, aAx, bv.x); aAy = fmaf(diA, aAy, bv.y);
    aBx = fmaf(diB, aBx, bv.x); aBy = fmaf(diB, aBy, bv.y);
    aAx = aAx > 0.f ? aAx : NEG_SLOPE * aAx;
    aAy = aAy > 0.f ? aAy : NEG_SLOPE * aAy;
    aBx = aBx > 0.f ? aBx : NEG_SLOPE * aBx;
    aBy = aBy > 0.f ? aBy : NEG_SLOPE * aBy;

    size_t rowA = (size_t)iA * D + 2 * lane;
    size_t rowB = (size_t)iB * D + 2 * lane;
    float2 xA = *(const float2*)&x[rowA];
    float2 xB = *(const float2*)&x[rowB];
    float vA0 = aAx + xA.x, vA1 = aAy + xA.y;
    float vB0 = aBx + xB.x, vB1 = aBy + xB.y;

    float sA1 = vA0 + vA1, sA2 = vA0 * vA0 + vA1 * vA1;
    float sB1 = vB0 + vB1, sB2 = vB0 * vB0 + vB1 * vB1;
    #pragma unroll
    for (int off = 1; off < 64; off <<= 1) {
        sA1 += __shfl_xor(sA1, off, 64);
        sA2 += __shfl_xor(sA2, off, 64);
        sB1 += __shfl_xor(sB1, off, 64);
        sB2 += __shfl_xor(sB2, off, 64);
    }
    float muA = sA1 * (1.f / 128.f);
    float varA = fmaxf(sA2 * (1.f / 128.f) - muA * muA, 0.f);
    float rsA = rsqrtf(varA + LN_EPS);
    float muB = sB1 * (1.f / 128.f);
    float varB = fmaxf(sB2 * (1.f / 128.f) - muB * muB, 0.f);
    float rsB = rsqrtf(varB + LN_EPS);

    float oA0 = (vA0 - muA) * rsA * gv.x + bt.x;
    float oA1 = (vA1 - muA) * rsA * gv.y + bt.y;
    float oB0 = (vB0 - muB) * rsB * gv.x + bt.x;
    float oB1 = (vB1 - muB) * rsB * gv.y + bt.y;

    int rA = wid * 2, rB = wid * 2 + 1;
    unsigned dwA = (unsigned)f2bf(oA0) | ((unsigned)f2bf(oA1) << 16);
    unsigned dwB = (unsigned)f2bf(oB0) | ((unsigned)f2bf(oB1) << 16);
    int byteA = (rA * 256 + lane * 4) ^ ((rA & 7) << 4);
    int byteB = (rB * 256 + lane * 4) ^ ((rB & 7) << 4);
    *(unsigned*)((char*)a_lds + byteA) = dwA;
    *(unsigned*)((char*)a_lds + byteB) = dwB;
    __syncthreads();

    int lrow = lane & 15, lgrp = lane >> 4;
    f32x4 acc = (f32x4){0.f, 0.f, 0.f, 0.f};
    #pragma unroll
    for (int kk = 0; kk < 4; ++kk) {
        int abyte = (lrow * 256 + kk * 64 + lgrp * 16) ^ ((lrow & 7) << 4);
        bf16x8 afrag = *(bf16x8*)((char*)a_lds + abyte);
        int bcol = wid * 16 + lrow;
        int bbyte = (bcol * 256 + kk * 64 + lgrp * 16) ^ ((bcol & 7) << 4);
        bf16x8 bfrag = *(bf16x8*)((char*)w_lds + bbyte);
        acc = __builtin_amdgcn_mfma_f32_16x16x32_bf16(afrag, bfrag, acc, 0, 0, 0);
    }
    #pragma unroll
    for (int r = 0; r < 4; ++r) {
        int grow = blockIdx.x * 16 + lgrp * 4 + r;
        hbf2[(size_t)grow * D + wid * 16 + lrow] = f2bf(dinv[grow] * acc[r]);
    }
}

// ---------------- layer 2: agg + bias + residual + LN2 + leaky (final f32 out) ----------------
__global__ __launch_bounds__(256) void agg_ln2(const unsigned* __restrict__ h,
                                               const float* __restrict__ x,
                                               const float* __restrict__ bias,
                                               const float* __restrict__ gamma,
                                               const float* __restrict__ beta,
                                               const float* __restrict__ dinv,
                                               const int2* __restrict__ rowinfo,
                                               const int* __restrict__ csr_src,
                                               float* __restrict__ out) {
    int wid = threadIdx.x >> 6;
    int lane = threadIdx.x & 63;
    int iA = blockIdx.x * 8 + wid * 2;   // NN = 50000 = 6250 * 8, exact
    int iB = iA + 1;
    float diA = dinv[iA], diB = dinv[iB];

    float aAx, aAy, aBx, aBy;
    bf2x(h[(size_t)iA * (D / 2) + lane], aAx, aAy);
    bf2x(h[(size_t)iB * (D / 2) + lane], aBx, aBy);

    int2 riA = rowinfo[iA];
    int2 riB = rowinfo[iB];
    int eA = __builtin_amdgcn_readfirstlane(riA.x);
    int eA1 = eA + __builtin_amdgcn_readfirstlane(riA.y);
    int eB = __builtin_amdgcn_readfirstlane(riB.x);
    int eB1 = eB + __builtin_amdgcn_readfirstlane(riB.y);
    agg_2node(h, csr_src, eA, eA1, eB, eB1, lane, aAx, aAy, aBx, aBy);

    float2 bv = *(const float2*)&bias[2 * lane];
    float2 gv = *(const float2*)&gamma[2 * lane];
    float2 bt = *(const float2*)&beta[2 * lane];

    aAx = fmaf(diA, aAx, bv.x); aAy = fmaf(diA, aAy, bv.y);
    aBx = fmaf(diB, aBx, bv.x); aBy = fmaf(diB, aBy, bv.y);
    size_t rowA = (size_t)iA * D + 2 * lane;
    size_t rowB = (size_t)iB * D + 2 * lane;
    float2 xA = *(const float2*)&x[rowA];
    float2 xB = *(const float2*)&x[rowB];
    float vA0 = aAx + xA.x, vA1 = aAy + xA.y;
    float vB0 = aBx + xB.x, vB1 = aBy + xB.y;

    float sA1 = vA0 + vA1, sA2 = vA0 * vA0 + vA1 * vA1;
    float sB1 = vB0 + vB1, sB2 = vB0 * vB0 + vB1 * vB1;
    #pragma unroll
    for (int off = 1; off < 64; off <<= 1) {
        sA1 += __shfl_xor(sA1, off, 64);
        sA2 += __shfl_xor(sA2, off, 64);
        sB1 += __shfl_xor(sB1, off, 64);
        sB2 += __shfl_xor(sB2, off, 64);
    }
    float muA = sA1 * (1.f / 128.f);
    float varA = fmaxf(sA2 * (1.f / 128.f) - muA * muA, 0.f);
    float rsA = rsqrtf(varA + LN_EPS);
    float muB = sB1 * (1.f / 128.f);
    float varB = fmaxf(sB2 * (1.f / 128.f) - muB * muB, 0.f);
    float rsB = rsqrtf(varB + LN_EPS);

    float oA0 = (vA0 - muA) * rsA * gv.x + bt.x;
    float oA1 = (vA1 - muA) * rsA * gv.y + bt.y;
    float oB0 = (vB0 - muB) * rsB * gv.x + bt.x;
    float oB1 = (vB1 - muB) * rsB * gv.y + bt.y;
    oA0 = oA0 > 0.f ? oA0 : NEG_SLOPE * oA0;
    oA1 = oA1 > 0.f ? oA1 : NEG_SLOPE * oA1;
    oB0 = oB0 > 0.f ? oB0 : NEG_SLOPE * oB0;
    oB1 = oB1 > 0.f ? oB1 : NEG_SLOPE * oB1;
    *(float2*)&out[rowA] = make_float2(oA0, oA1);
    *(float2*)&out[rowB] = make_float2(oB0, oB1);
}

extern "C" void kernel_launch(void* const* d_in, const int* in_sizes, int n_in,
                              void* d_out, int out_size, void* d_ws, size_t ws_size,
                              hipStream_t stream) {
    const float* x    = (const float*)d_in[0];
    const int*   ei   = (const int*)d_in[1];   // [2, NE]: row0 src, row1 dst
    const float* W1   = (const float*)d_in[2];
    const float* b1   = (const float*)d_in[3];
    const float* ln1g = (const float*)d_in[4];
    const float* ln1b = (const float*)d_in[5];
    const float* W2   = (const float*)d_in[6];
    const float* b2   = (const float*)d_in[7];
    const float* ln2g = (const float*)d_in[8];
    const float* ln2b = (const float*)d_in[9];
    float* out = (float*)d_out;

    const int* srcp = ei;
    const int* dstp = ei + NE;

    char* ws = (char*)d_ws;
    size_t p = 0;
    auto alloc = [&](size_t bytes) {
        char* r = ws + p;
        p += (bytes + 255) & ~(size_t)255;
        return r;
    };
    int*   bcursor  = (int*)alloc((NB + 1) * 4);         // [NB] = ticket
    int2*  rowinfo  = (int2*)alloc((size_t)NN * 8);
    float* dinv     = (float*)alloc(NN * 4);
    int2*  bedge    = (int2*)alloc((size_t)NB * CAP * 8);
    int*   csr_src  = (int*)alloc(((size_t)NE + 8 * NN) * 4);  // padded CSR, 4 B/edge
    unsigned short* hbf  = (unsigned short*)alloc((size_t)(NN + 8) * D * 2);  // +zero row
    unsigned short* hbf2 = (unsigned short*)alloc((size_t)(NN + 8) * D * 2);  // +zero row
    unsigned short* wt1  = (unsigned short*)alloc(D * D * 2);
    unsigned short* wt2  = (unsigned short*)alloc(D * D * 2);

    hipMemsetAsync(bcursor, 0, (NB + 1) * 4, stream);

    wt_pack2<<<2 * D * D / 256, 256, 0, stream>>>(W1, W2, wt1, wt2, hbf, hbf2);

    bucket_scatter<<<NCH, 256, 0, stream>>>(srcp, dstp, bcursor, bedge);
    node_count<<<NB, 256, 0, stream>>>(bedge, bcursor, dinv, rowinfo, &bcursor[NB]);
    gemm_mfma<<<(NN + 63) / 64, 256, 0, stream>>>(x, wt1, dinv, hbf, NN);
    csr_scatter<<<NB, 256, 0, stream>>>(bedge, bcursor, rowinfo, csr_src);

    // Layer 1 (+ fused GEMM2): hbf2 = dinv ⊙ ( LN1(leaky(agg(hbf)+b1)+x) @ W2 )
    agg_ln1_gemm<<<NN / 16, 512, 0, stream>>>((const unsigned*)hbf, x, b1, ln1g, ln1b,
                                              dinv, rowinfo, csr_src, wt2, hbf2);

    // Layer 2: out = leaky(LN2(agg(hbf2)+b2+x))
    agg_ln2<<<NN / 8, 256, 0, stream>>>((const unsigned*)hbf2, x, b2, ln2g, ln2b,
                                        dinv, rowinfo, csr_src, out);
}

// Round 13
// 124.305 us; speedup vs baseline: 1.2050x; 1.0466x over previous
//
#include <hip/hip_runtime.h>
#include <hip/hip_bf16.h>

#define NN 50000
#define NE 800000
#define D 128
#define NEG_SLOPE 0.01f
#define LN_EPS 1e-5f

#define NPB 256                 // nodes per bucket (bucket = dst >> 8)
#define NB 196                  // ceil(NN / NPB); NB*256 = 50176
#define CAP 6144                // per-bucket bedge capacity (avg 4082, max ~4340)
#define ECH 8192                // edges per bucket-workgroup
#define NCH ((NE + ECH - 1) / ECH)  // 98
#define NWPK 128                // wt_pack blocks appended to fused_a

typedef __attribute__((ext_vector_type(8))) short bf16x8;
typedef __attribute__((ext_vector_type(4))) float f32x4;
typedef __attribute__((ext_vector_type(4))) int i32x4;

// f32 -> bf16 round-to-nearest-even (finite values)
__device__ inline unsigned short f2bf(float f) {
    unsigned u = __float_as_uint(f);
    unsigned r = 0x7FFFu + ((u >> 16) & 1u);
    return (unsigned short)((u + r) >> 16);
}
// unpack one dword = 2 bf16 -> 2 floats
__device__ inline void bf2x(unsigned u, float& lo, float& hi) {
    lo = __uint_as_float(u << 16);
    hi = __uint_as_float(u & 0xFFFF0000u);
}

// ---------------- fused_a: bucket scatter (98 blocks) || wt_pack (128 blocks) ----------------
__global__ __launch_bounds__(256) void fused_a(const int* __restrict__ src,
                                               const int* __restrict__ dst,
                                               int* __restrict__ bcursor,
                                               int2* __restrict__ bedge,
                                               const float* __restrict__ W1,
                                               const float* __restrict__ W2,
                                               unsigned short* __restrict__ WT1,
                                               unsigned short* __restrict__ WT2,
                                               unsigned short* __restrict__ hbf,
                                               unsigned short* __restrict__ hbf2) {
    __shared__ int hist[NB], lcur[NB], gbase[NB];
    int bid = blockIdx.x, t = threadIdx.x;
    if (bid < NCH) {
        int e0 = bid * ECH;
        int ecnt = min(ECH, NE - e0);
        if (t < NB) hist[t] = 0;
        __syncthreads();
        for (int k = t; k < ecnt; k += 256) atomicAdd(&hist[dst[e0 + k] >> 8], 1);
        __syncthreads();
        if (t < NB) {
            gbase[t] = atomicAdd(&bcursor[t], hist[t]);   // reserve exclusive run
            lcur[t] = 0;
        }
        __syncthreads();
        for (int k = t; k < ecnt; k += 256) {
            int s = src[e0 + k], d = dst[e0 + k];
            int b = d >> 8;
            int p = atomicAdd(&lcur[b], 1);
            bedge[(size_t)b * CAP + gbase[b] + p] = make_int2(s, d);
        }
    } else {
        int tid = (bid - NCH) * 256 + t;                  // [0, 32768)
        if (tid < 32) {
            uint4 z = make_uint4(0u, 0u, 0u, 0u);
            if (tid < 16) *(uint4*)&hbf[(size_t)NN * D + tid * 8] = z;
            else          *(uint4*)&hbf2[(size_t)NN * D + (tid - 16) * 8] = z;
        }
        const float* W = (tid < D * D) ? W1 : W2;
        unsigned short* WT = (tid < D * D) ? WT1 : WT2;
        int id = tid & (D * D - 1);
        int nn = id & 127, k = id >> 7;
        WT[nn * 128 + k] = f2bf(W[k * 128 + nn]);
    }
}

// ---------------- fused_b: per-bucket histogram -> dinv/rowinfo -> padded CSR scatter ----------------
__global__ __launch_bounds__(256) void fused_b(const int2* __restrict__ bedge,
                                               const int* __restrict__ bcnt,
                                               float* __restrict__ dinv,
                                               int2* __restrict__ rowinfo,
                                               int* __restrict__ ticket,
                                               int* __restrict__ csr_src) {
    __shared__ int h[NPB];
    __shared__ int tmp[256];
    __shared__ int rl[NPB], cur[NPB];
    __shared__ int base;
    int b = blockIdx.x, t = threadIdx.x;
    h[t] = 0;
    __syncthreads();
    int s0 = b * CAP, s1 = s0 + bcnt[b];
    for (int k = s0 + t; k < s1; k += 256) atomicAdd(&h[bedge[k].y & 255], 1);
    __syncthreads();
    int deg = h[t];
    int node = b * NPB + t;
    int pdeg = (deg + 7) & ~7;                    // pad to multiple of 8
    tmp[t] = pdeg;
    __syncthreads();
    for (int off = 1; off < 256; off <<= 1) {
        int uu = (t >= off) ? tmp[t - off] : 0;
        __syncthreads();
        tmp[t] += uu;
        __syncthreads();
    }
    if (t == 255) base = atomicAdd(ticket, tmp[255]);
    __syncthreads();
    int start = base + tmp[t] - pdeg;
    rl[t] = start;
    cur[t] = 0;
    if (node < NN) {
        dinv[node] = rsqrtf((float)(deg + 1));    // +1: self-loop
        rowinfo[node] = make_int2(start, pdeg);
    }
    __syncthreads();
    for (int k = s0 + t; k < s1; k += 256) {      // bedge slice L2-hot from pass 1
        int2 eg = bedge[k];
        int li = eg.y & 255;
        int p = atomicAdd(&cur[li], 1);
        csr_src[rl[li] + p] = eg.x;
    }
    __syncthreads();
    int dgc = cur[t];
    int pend = (dgc + 7) & ~7;
    for (int k = dgc; k < pend; ++k)
        csr_src[rl[t] + k] = NN;                  // zero-row pad
}

// ---------------- MFMA GEMM1: hbf = bf16( dinv ⊙ (x @ W1) ) ----------------
__global__ __launch_bounds__(256) void gemm_mfma(const float* __restrict__ A,
                                                 const unsigned short* __restrict__ WT,
                                                 const float* __restrict__ dinv,
                                                 unsigned short* __restrict__ out, int n) {
    __shared__ __align__(16) unsigned short a_lds[64 * 128];   // 16 KB
    __shared__ __align__(16) unsigned short w_lds[128 * 128];  // 32 KB
    int t = threadIdx.x;
    int m0 = blockIdx.x * 64;

    #pragma unroll
    for (int it = 0; it < 8; ++it) {
        int idx = it * 256 + t;
        int row = idx >> 4, c = idx & 15;
        uint4 v = *(const uint4*)&WT[row * 128 + c * 8];
        int byte = (row * 256 + c * 16) ^ ((row & 7) << 4);
        *(uint4*)((char*)w_lds + byte) = v;
    }
    #pragma unroll
    for (int it = 0; it < 4; ++it) {
        int idx = it * 256 + t;
        int row = idx >> 4, c = idx & 15;
        int grow = m0 + row;
        uint4 w = make_uint4(0u, 0u, 0u, 0u);
        if (grow < n) {
            float4 v0 = *(const float4*)&A[(size_t)grow * D + c * 8];
            float4 v1 = *(const float4*)&A[(size_t)grow * D + c * 8 + 4];
            w.x = (unsigned)f2bf(v0.x) | ((unsigned)f2bf(v0.y) << 16);
            w.y = (unsigned)f2bf(v0.z) | ((unsigned)f2bf(v0.w) << 16);
            w.z = (unsigned)f2bf(v1.x) | ((unsigned)f2bf(v1.y) << 16);
            w.w = (unsigned)f2bf(v1.z) | ((unsigned)f2bf(v1.w) << 16);
        }
        int byte = (row * 256 + c * 16) ^ ((row & 7) << 4);
        *(uint4*)((char*)a_lds + byte) = w;
    }
    __syncthreads();

    int wv = t >> 6, l = t & 63;
    int lrow = l & 15, lgrp = l >> 4;
    int arow = wv * 16 + lrow;

    f32x4 acc[8];
    #pragma unroll
    for (int nf = 0; nf < 8; ++nf) acc[nf] = (f32x4){0.f, 0.f, 0.f, 0.f};

    #pragma unroll
    for (int kk = 0; kk < 4; ++kk) {
        int abyte = (arow * 256 + kk * 64 + lgrp * 16) ^ ((arow & 7) << 4);
        bf16x8 afrag = *(bf16x8*)((char*)a_lds + abyte);
        #pragma unroll
        for (int nf = 0; nf < 8; ++nf) {
            int bcol = nf * 16 + lrow;
            int bbyte = (bcol * 256 + kk * 64 + lgrp * 16) ^ ((bcol & 7) << 4);
            bf16x8 bfrag = *(bf16x8*)((char*)w_lds + bbyte);
            acc[nf] = __builtin_amdgcn_mfma_f32_16x16x32_bf16(afrag, bfrag, acc[nf], 0, 0, 0);
        }
    }

    #pragma unroll
    for (int r = 0; r < 4; ++r) {
        int grow = m0 + wv * 16 + lgrp * 4 + r;
        if (grow < n) {
            float dv = dinv[grow];
            #pragma unroll
            for (int nf = 0; nf < 8; ++nf)
                out[(size_t)grow * D + nf * 16 + lrow] = f2bf(dv * acc[nf][r]);
        }
    }
}

// ---------------- aggregation helpers (coef-free: pure adds) ----------------

__device__ inline void agg8s(const unsigned* __restrict__ h, const int* __restrict__ csr,
                             int e, int lane, float& ax_, float& ay_) {
    i32x4 s0 = __builtin_nontemporal_load((const i32x4*)(csr + e));
    i32x4 s1 = __builtin_nontemporal_load((const i32x4*)(csr + e + 4));
    unsigned g0 = h[(size_t)s0[0] * (D / 2) + lane];
    unsigned g1 = h[(size_t)s0[1] * (D / 2) + lane];
    unsigned g2 = h[(size_t)s0[2] * (D / 2) + lane];
    unsigned g3 = h[(size_t)s0[3] * (D / 2) + lane];
    unsigned g4 = h[(size_t)s1[0] * (D / 2) + lane];
    unsigned g5 = h[(size_t)s1[1] * (D / 2) + lane];
    unsigned g6 = h[(size_t)s1[2] * (D / 2) + lane];
    unsigned g7 = h[(size_t)s1[3] * (D / 2) + lane];
    float lo, hi;
    bf2x(g0, lo, hi); ax_ += lo; ay_ += hi;
    bf2x(g1, lo, hi); ax_ += lo; ay_ += hi;
    bf2x(g2, lo, hi); ax_ += lo; ay_ += hi;
    bf2x(g3, lo, hi); ax_ += lo; ay_ += hi;
    bf2x(g4, lo, hi); ax_ += lo; ay_ += hi;
    bf2x(g5, lo, hi); ax_ += lo; ay_ += hi;
    bf2x(g6, lo, hi); ax_ += lo; ay_ += hi;
    bf2x(g7, lo, hi); ax_ += lo; ay_ += hi;
}

// joint 2-node loop: 16-deep per node (32 gathers in flight), then 8-deep drains
__device__ inline void agg_2node(const unsigned* __restrict__ h,
                                 const int* __restrict__ csr,
                                 int eA, int eA1, int eB, int eB1, int lane,
                                 float& aAx, float& aAy, float& aBx, float& aBy) {
    while (eA + 16 <= eA1 && eB + 16 <= eB1) {
        i32x4 sA0 = __builtin_nontemporal_load((const i32x4*)(csr + eA));
        i32x4 sA1 = __builtin_nontemporal_load((const i32x4*)(csr + eA + 4));
        i32x4 sA2 = __builtin_nontemporal_load((const i32x4*)(csr + eA + 8));
        i32x4 sA3 = __builtin_nontemporal_load((const i32x4*)(csr + eA + 12));
        i32x4 sB0 = __builtin_nontemporal_load((const i32x4*)(csr + eB));
        i32x4 sB1 = __builtin_nontemporal_load((const i32x4*)(csr + eB + 4));
        i32x4 sB2 = __builtin_nontemporal_load((const i32x4*)(csr + eB + 8));
        i32x4 sB3 = __builtin_nontemporal_load((const i32x4*)(csr + eB + 12));
        unsigned gA0 = h[(size_t)sA0[0] * (D / 2) + lane];
        unsigned gA1 = h[(size_t)sA0[1] * (D / 2) + lane];
        unsigned gA2 = h[(size_t)sA0[2] * (D / 2) + lane];
        unsigned gA3 = h[(size_t)sA0[3] * (D / 2) + lane];
        unsigned gA4 = h[(size_t)sA1[0] * (D / 2) + lane];
        unsigned gA5 = h[(size_t)sA1[1] * (D / 2) + lane];
        unsigned gA6 = h[(size_t)sA1[2] * (D / 2) + lane];
        unsigned gA7 = h[(size_t)sA1[3] * (D / 2) + lane];
        unsigned gA8 = h[(size_t)sA2[0] * (D / 2) + lane];
        unsigned gA9 = h[(size_t)sA2[1] * (D / 2) + lane];
        unsigned gAa = h[(size_t)sA2[2] * (D / 2) + lane];
        unsigned gAb = h[(size_t)sA2[3] * (D / 2) + lane];
        unsigned gAc = h[(size_t)sA3[0] * (D / 2) + lane];
        unsigned gAd = h[(size_t)sA3[1] * (D / 2) + lane];
        unsigned gAe = h[(size_t)sA3[2] * (D / 2) + lane];
        unsigned gAf = h[(size_t)sA3[3] * (D / 2) + lane];
        unsigned gB0 = h[(size_t)sB0[0] * (D / 2) + lane];
        unsigned gB1 = h[(size_t)sB0[1] * (D / 2) + lane];
        unsigned gB2 = h[(size_t)sB0[2] * (D / 2) + lane];
        unsigned gB3 = h[(size_t)sB0[3] * (D / 2) + lane];
        unsigned gB4 = h[(size_t)sB1[0] * (D / 2) + lane];
        unsigned gB5 = h[(size_t)sB1[1] * (D / 2) + lane];
        unsigned gB6 = h[(size_t)sB1[2] * (D / 2) + lane];
        unsigned gB7 = h[(size_t)sB1[3] * (D / 2) + lane];
        unsigned gB8 = h[(size_t)sB2[0] * (D / 2) + lane];
        unsigned gB9 = h[(size_t)sB2[1] * (D / 2) + lane];
        unsigned gBa = h[(size_t)sB2[2] * (D / 2) + lane];
        unsigned gBb = h[(size_t)sB2[3] * (D / 2) + lane];
        unsigned gBc = h[(size_t)sB3[0] * (D / 2) + lane];
        unsigned gBd = h[(size_t)sB3[1] * (D / 2) + lane];
        unsigned gBe = h[(size_t)sB3[2] * (D / 2) + lane];
        unsigned gBf = h[(size_t)sB3[3] * (D / 2) + lane];
        float lo, hi;
        bf2x(gA0, lo, hi); aAx += lo; aAy += hi;
        bf2x(gA1, lo, hi); aAx += lo; aAy += hi;
        bf2x(gA2, lo, hi); aAx += lo; aAy += hi;
        bf2x(gA3, lo, hi); aAx += lo; aAy += hi;
        bf2x(gA4, lo, hi); aAx += lo; aAy += hi;
        bf2x(gA5, lo, hi); aAx += lo; aAy += hi;
        bf2x(gA6, lo, hi); aAx += lo; aAy += hi;
        bf2x(gA7, lo, hi); aAx += lo; aAy += hi;
        bf2x(gA8, lo, hi); aAx += lo; aAy += hi;
        bf2x(gA9, lo, hi); aAx += lo; aAy += hi;
        bf2x(gAa, lo, hi); aAx += lo; aAy += hi;
        bf2x(gAb, lo, hi); aAx += lo; aAy += hi;
        bf2x(gAc, lo, hi); aAx += lo; aAy += hi;
        bf2x(gAd, lo, hi); aAx += lo; aAy += hi;
        bf2x(gAe, lo, hi); aAx += lo; aAy += hi;
        bf2x(gAf, lo, hi); aAx += lo; aAy += hi;
        bf2x(gB0, lo, hi); aBx += lo; aBy += hi;
        bf2x(gB1, lo, hi); aBx += lo; aBy += hi;
        bf2x(gB2, lo, hi); aBx += lo; aBy += hi;
        bf2x(gB3, lo, hi); aBx += lo; aBy += hi;
        bf2x(gB4, lo, hi); aBx += lo; aBy += hi;
        bf2x(gB5, lo, hi); aBx += lo; aBy += hi;
        bf2x(gB6, lo, hi); aBx += lo; aBy += hi;
        bf2x(gB7, lo, hi); aBx += lo; aBy += hi;
        bf2x(gB8, lo, hi); aBx += lo; aBy += hi;
        bf2x(gB9, lo, hi); aBx += lo; aBy += hi;
        bf2x(gBa, lo, hi); aBx += lo; aBy += hi;
        bf2x(gBb, lo, hi); aBx += lo; aBy += hi;
        bf2x(gBc, lo, hi); aBx += lo; aBy += hi;
        bf2x(gBd, lo, hi); aBx += lo; aBy += hi;
        bf2x(gBe, lo, hi); aBx += lo; aBy += hi;
        bf2x(gBf, lo, hi); aBx += lo; aBy += hi;
        eA += 16; eB += 16;
    }
    while (eA + 8 <= eA1 && eB + 8 <= eB1) {
        agg8s(h, csr, eA, lane, aAx, aAy);
        agg8s(h, csr, eB, lane, aBx, aBy);
        eA += 8; eB += 8;
    }
    while (eA < eA1) { agg8s(h, csr, eA, lane, aAx, aAy); eA += 8; }
    while (eB < eB1) { agg8s(h, csr, eB, lane, aBx, aBy); eB += 8; }
}

// ---------------- layer 1: agg + bias + leaky + residual + LN1 + GEMM2 (fused MFMA) ----------------
__global__ __launch_bounds__(512) void agg_ln1_gemm(const unsigned* __restrict__ h,
                                                    const float* __restrict__ x,
                                                    const float* __restrict__ bias,
                                                    const float* __restrict__ gamma,
                                                    const float* __restrict__ beta,
                                                    const float* __restrict__ dinv,
                                                    const int2* __restrict__ rowinfo,
                                                    const int* __restrict__ csr_src,
                                                    const unsigned short* __restrict__ wt2,
                                                    unsigned short* __restrict__ hbf2) {
    __shared__ __align__(16) unsigned short w_lds[128 * 128];  // 32 KB
    __shared__ __align__(16) unsigned short a_lds[16 * 128];   // 4 KB
    int t = threadIdx.x;

    #pragma unroll
    for (int it = 0; it < 4; ++it) {
        int idx = it * 512 + t;
        int row = idx >> 4, c = idx & 15;
        uint4 v = *(const uint4*)&wt2[row * 128 + c * 8];
        int byte = (row * 256 + c * 16) ^ ((row & 7) << 4);
        *(uint4*)((char*)w_lds + byte) = v;
    }

    int wid = t >> 6, lane = t & 63;
    int iA = blockIdx.x * 16 + wid * 2;   // NN = 50000 = 3125 * 16, exact
    int iB = iA + 1;
    float diA = dinv[iA], diB = dinv[iB];

    float aAx, aAy, aBx, aBy;
    bf2x(h[(size_t)iA * (D / 2) + lane], aAx, aAy);
    bf2x(h[(size_t)iB * (D / 2) + lane], aBx, aBy);

    int2 riA = rowinfo[iA];
    int2 riB = rowinfo[iB];
    int eA = __builtin_amdgcn_readfirstlane(riA.x);
    int eA1 = eA + __builtin_amdgcn_readfirstlane(riA.y);
    int eB = __builtin_amdgcn_readfirstlane(riB.x);
    int eB1 = eB + __builtin_amdgcn_readfirstlane(riB.y);
    agg_2node(h, csr_src, eA, eA1, eB, eB1, lane, aAx, aAy, aBx, aBy);

    float2 bv = *(const float2*)&bias[2 * lane];
    float2 gv = *(const float2*)&gamma[2 * lane];
    float2 bt = *(const float2*)&beta[2 * lane];

    aAx = fmaf(diA, aAx, bv.x); aAy = fmaf(diA, aAy, bv.y);
    aBx = fmaf(diB, aBx, bv.x); aBy = fmaf(diB, aBy, bv.y);
    aAx = aAx > 0.f ? aAx : NEG_SLOPE * aAx;
    aAy = aAy > 0.f ? aAy : NEG_SLOPE * aAy;
    aBx = aBx > 0.f ? aBx : NEG_SLOPE * aBx;
    aBy = aBy > 0.f ? aBy : NEG_SLOPE * aBy;

    size_t rowA = (size_t)iA * D + 2 * lane;
    size_t rowB = (size_t)iB * D + 2 * lane;
    float2 xA = *(const float2*)&x[rowA];
    float2 xB = *(const float2*)&x[rowB];
    float vA0 = aAx + xA.x, vA1 = aAy + xA.y;
    float vB0 = aBx + xB.x, vB1 = aBy + xB.y;

    float sA1 = vA0 + vA1, sA2 = vA0 * vA0 + vA1 * vA1;
    float sB1 = vB0 + vB1, sB2 = vB0 * vB0 + vB1 * vB1;
    #pragma unroll
    for (int off = 1; off < 64; off <<= 1) {
        sA1 += __shfl_xor(sA1, off, 64);
        sA2 += __shfl_xor(sA2, off, 64);
        sB1 += __shfl_xor(sB1, off, 64);
        sB2 += __shfl_xor(sB2, off, 64);
    }
    float muA = sA1 * (1.f / 128.f);
    float varA = fmaxf(sA2 * (1.f / 128.f) - muA * muA, 0.f);
    float rsA = rsqrtf(varA + LN_EPS);
    float muB = sB1 * (1.f / 128.f);
    float varB = fmaxf(sB2 * (1.f / 128.f) - muB * muB, 0.f);
    float rsB = rsqrtf(varB + LN_EPS);

    float oA0 = (vA0 - muA) * rsA * gv.x + bt.x;
    float oA1 = (vA1 - muA) * rsA * gv.y + bt.y;
    float oB0 = (vB0 - muB) * rsB * gv.x + bt.x;
    float oB1 = (vB1 - muB) * rsB * gv.y + bt.y;

    int rA = wid * 2, rB = wid * 2 + 1;
    unsigned dwA = (unsigned)f2bf(oA0) | ((unsigned)f2bf(oA1) << 16);
    unsigned dwB = (unsigned)f2bf(oB0) | ((unsigned)f2bf(oB1) << 16);
    int byteA = (rA * 256 + lane * 4) ^ ((rA & 7) << 4);
    int byteB = (rB * 256 + lane * 4) ^ ((rB & 7) << 4);
    *(unsigned*)((char*)a_lds + byteA) = dwA;
    *(unsigned*)((char*)a_lds + byteB) = dwB;
    __syncthreads();

    int lrow = lane & 15, lgrp = lane >> 4;
    f32x4 acc = (f32x4){0.f, 0.f, 0.f, 0.f};
    #pragma unroll
    for (int kk = 0; kk < 4; ++kk) {
        int abyte = (lrow * 256 + kk * 64 + lgrp * 16) ^ ((lrow & 7) << 4);
        bf16x8 afrag = *(bf16x8*)((char*)a_lds + abyte);
        int bcol = wid * 16 + lrow;
        int bbyte = (bcol * 256 + kk * 64 + lgrp * 16) ^ ((bcol & 7) << 4);
        bf16x8 bfrag = *(bf16x8*)((char*)w_lds + bbyte);
        acc = __builtin_amdgcn_mfma_f32_16x16x32_bf16(afrag, bfrag, acc, 0, 0, 0);
    }
    #pragma unroll
    for (int r = 0; r < 4; ++r) {
        int grow = blockIdx.x * 16 + lgrp * 4 + r;
        hbf2[(size_t)grow * D + wid * 16 + lrow] = f2bf(dinv[grow] * acc[r]);
    }
}

// ---------------- layer 2: agg + bias + residual + LN2 + leaky (final f32 out) ----------------
__global__ __launch_bounds__(256) void agg_ln2(const unsigned* __restrict__ h,
                                               const float* __restrict__ x,
                                               const float* __restrict__ bias,
                                               const float* __restrict__ gamma,
                                               const float* __restrict__ beta,
                                               const float* __restrict__ dinv,
                                               const int2* __restrict__ rowinfo,
                                               const int* __restrict__ csr_src,
                                               float* __restrict__ out) {
    int wid = threadIdx.x >> 6;
    int lane = threadIdx.x & 63;
    int iA = blockIdx.x * 8 + wid * 2;   // NN = 50000 = 6250 * 8, exact
    int iB = iA + 1;
    float diA = dinv[iA], diB = dinv[iB];

    float aAx, aAy, aBx, aBy;
    bf2x(h[(size_t)iA * (D / 2) + lane], aAx, aAy);
    bf2x(h[(size_t)iB * (D / 2) + lane], aBx, aBy);

    int2 riA = rowinfo[iA];
    int2 riB = rowinfo[iB];
    int eA = __builtin_amdgcn_readfirstlane(riA.x);
    int eA1 = eA + __builtin_amdgcn_readfirstlane(riA.y);
    int eB = __builtin_amdgcn_readfirstlane(riB.x);
    int eB1 = eB + __builtin_amdgcn_readfirstlane(riB.y);
    agg_2node(h, csr_src, eA, eA1, eB, eB1, lane, aAx, aAy, aBx, aBy);

    float2 bv = *(const float2*)&bias[2 * lane];
    float2 gv = *(const float2*)&gamma[2 * lane];
    float2 bt = *(const float2*)&beta[2 * lane];

    aAx = fmaf(diA, aAx, bv.x); aAy = fmaf(diA, aAy, bv.y);
    aBx = fmaf(diB, aBx, bv.x); aBy = fmaf(diB, aBy, bv.y);
    size_t rowA = (size_t)iA * D + 2 * lane;
    size_t rowB = (size_t)iB * D + 2 * lane;
    float2 xA = *(const float2*)&x[rowA];
    float2 xB = *(const float2*)&x[rowB];
    float vA0 = aAx + xA.x, vA1 = aAy + xA.y;
    float vB0 = aBx + xB.x, vB1 = aBy + xB.y;

    float sA1 = vA0 + vA1, sA2 = vA0 * vA0 + vA1 * vA1;
    float sB1 = vB0 + vB1, sB2 = vB0 * vB0 + vB1 * vB1;
    #pragma unroll
    for (int off = 1; off < 64; off <<= 1) {
        sA1 += __shfl_xor(sA1, off, 64);
        sA2 += __shfl_xor(sA2, off, 64);
        sB1 += __shfl_xor(sB1, off, 64);
        sB2 += __shfl_xor(sB2, off, 64);
    }
    float muA = sA1 * (1.f / 128.f);
    float varA = fmaxf(sA2 * (1.f / 128.f) - muA * muA, 0.f);
    float rsA = rsqrtf(varA + LN_EPS);
    float muB = sB1 * (1.f / 128.f);
    float varB = fmaxf(sB2 * (1.f / 128.f) - muB * muB, 0.f);
    float rsB = rsqrtf(varB + LN_EPS);

    float oA0 = (vA0 - muA) * rsA * gv.x + bt.x;
    float oA1 = (vA1 - muA) * rsA * gv.y + bt.y;
    float oB0 = (vB0 - muB) * rsB * gv.x + bt.x;
    float oB1 = (vB1 - muB) * rsB * gv.y + bt.y;
    oA0 = oA0 > 0.f ? oA0 : NEG_SLOPE * oA0;
    oA1 = oA1 > 0.f ? oA1 : NEG_SLOPE * oA1;
    oB0 = oB0 > 0.f ? oB0 : NEG_SLOPE * oB0;
    oB1 = oB1 > 0.f ? oB1 : NEG_SLOPE * oB1;
    *(float2*)&out[rowA] = make_float2(oA0, oA1);
    *(float2*)&out[rowB] = make_float2(oB0, oB1);
}

extern "C" void kernel_launch(void* const* d_in, const int* in_sizes, int n_in,
                              void* d_out, int out_size, void* d_ws, size_t ws_size,
                              hipStream_t stream) {
    const float* x    = (const float*)d_in[0];
    const int*   ei   = (const int*)d_in[1];   // [2, NE]: row0 src, row1 dst
    const float* W1   = (const float*)d_in[2];
    const float* b1   = (const float*)d_in[3];
    const float* ln1g = (const float*)d_in[4];
    const float* ln1b = (const float*)d_in[5];
    const float* W2   = (const float*)d_in[6];
    const float* b2   = (const float*)d_in[7];
    const float* ln2g = (const float*)d_in[8];
    const float* ln2b = (const float*)d_in[9];
    float* out = (float*)d_out;

    const int* srcp = ei;
    const int* dstp = ei + NE;

    char* ws = (char*)d_ws;
    size_t p = 0;
    auto alloc = [&](size_t bytes) {
        char* r = ws + p;
        p += (bytes + 255) & ~(size_t)255;
        return r;
    };
    int*   bcursor  = (int*)alloc((NB + 1) * 4);         // [NB] = ticket
    int2*  rowinfo  = (int2*)alloc((size_t)NN * 8);
    float* dinv     = (float*)alloc(NN * 4);
    int2*  bedge    = (int2*)alloc((size_t)NB * CAP * 8);
    int*   csr_src  = (int*)alloc(((size_t)NE + 8 * NN) * 4);  // padded CSR, 4 B/edge
    unsigned short* hbf  = (unsigned short*)alloc((size_t)(NN + 8) * D * 2);  // +zero row
    unsigned short* hbf2 = (unsigned short*)alloc((size_t)(NN + 8) * D * 2);  // +zero row
    unsigned short* wt1  = (unsigned short*)alloc(D * D * 2);
    unsigned short* wt2  = (unsigned short*)alloc(D * D * 2);

    hipMemsetAsync(bcursor, 0, (NB + 1) * 4, stream);

    // bucket scatter || weight pack (+ zero pad rows)
    fused_a<<<NCH + NWPK, 256, 0, stream>>>(srcp, dstp, bcursor, bedge,
                                            W1, W2, wt1, wt2, hbf, hbf2);

    // per-bucket: histogram -> dinv/rowinfo -> padded CSR
    fused_b<<<NB, 256, 0, stream>>>(bedge, bcursor, dinv, rowinfo,
                                    &bcursor[NB], csr_src);

    // GEMM1: hbf = dinv ⊙ bf16(x @ W1)
    gemm_mfma<<<(NN + 63) / 64, 256, 0, stream>>>(x, wt1, dinv, hbf, NN);

    // Layer 1 (+ fused GEMM2): hbf2 = dinv ⊙ ( LN1(leaky(agg(hbf)+b1)+x) @ W2 )
    agg_ln1_gemm<<<NN / 16, 512, 0, stream>>>((const unsigned*)hbf, x, b1, ln1g, ln1b,
                                              dinv, rowinfo, csr_src, wt2, hbf2);

    // Layer 2: out = leaky(LN2(agg(hbf2)+b2+x))
    agg_ln2<<<NN / 8, 256, 0, stream>>>((const unsigned*)hbf2, x, b2, ln2g, ln2b,
                                        dinv, rowinfo, csr_src, out);
}